// Round 1
// baseline (423.395 us; speedup 1.0000x reference)
//
#include <hip/hip_runtime.h>

#define N_ROWS 8192
#define IN_DIM 1024
#define EMBD   1024
#define KF     8

// ---------------------------------------------------------------------------
// K1: extract per-row feature indices (ascending) + per-feature counts
// one wave (64 lanes) per sample row; lane l owns columns [l*16, l*16+16)
__global__ void extract_rows(const int* __restrict__ x,
                             int* __restrict__ idx,
                             int* __restrict__ cnt) {
    const int r    = blockIdx.x * 4 + (threadIdx.x >> 6);
    const int lane = threadIdx.x & 63;
    const int* row = x + (size_t)r * IN_DIM;

    int vals[16];
    #pragma unroll
    for (int j = 0; j < 4; ++j) {
        int4 v = ((const int4*)row)[lane * 4 + j];
        vals[j * 4 + 0] = v.x;
        vals[j * 4 + 1] = v.y;
        vals[j * 4 + 2] = v.z;
        vals[j * 4 + 3] = v.w;
    }
    int c = 0;
    #pragma unroll
    for (int j = 0; j < 16; ++j) c += (vals[j] != 0);

    // inclusive wave scan -> exclusive offset
    int s = c;
    #pragma unroll
    for (int o = 1; o < 64; o <<= 1) {
        int t = __shfl_up(s, o, 64);
        if (lane >= o) s += t;
    }
    int pos = s - c;

    #pragma unroll
    for (int j = 0; j < 16; ++j) {
        if (vals[j] != 0) {
            int col = lane * 16 + j;
            if (pos < KF) idx[r * KF + pos] = col;
            pos++;
            atomicAdd(&cnt[col], 1);
        }
    }
}

// K2: dinv per feature node
__global__ void compute_dinv(const int* __restrict__ cnt, float* __restrict__ d) {
    int c = blockIdx.x * 256 + threadIdx.x;
    d[c] = rsqrtf((float)cnt[c] + 1.0f);
}

// K3: co-occurrence matrix M[c][c'] += 1 for every ordered pair within a row
__global__ void build_M(const int* __restrict__ idx, float* __restrict__ M) {
    const int r = blockIdx.x * 4 + (threadIdx.x >> 6);
    const int t = threadIdx.x & 63;
    const int i = t >> 3, j = t & 7;
    int ci = idx[r * KF + i];
    int cj = idx[r * KF + j];
    atomicAdd(&M[ci * IN_DIM + cj], 1.0f);
}

// K3b: scale columns of M by d[c']  (M~ = M * diag(d))
__global__ void scale_M(float* __restrict__ M, const float* __restrict__ d) {
    int i = blockIdx.x * 256 + threadIdx.x;     // 1M elements
    M[i] *= d[i & (IN_DIM - 1)];
}

// ---------------------------------------------------------------------------
// f32 SIMT GEMM: D[1024,1024] = A[1024,1024] @ B[1024,1024], row-major
// 64x64 tile per block, BK=16, 256 threads, 4x4 per-thread tile
__global__ __launch_bounds__(256) void gemm_f32(const float* __restrict__ A,
                                                const float* __restrict__ B,
                                                float* __restrict__ D) {
    __shared__ float As[16][68];   // [k][m], padded: 68*4B = 17*16B (aligned + conflict break)
    __shared__ float Bs[16][64];   // [k][n]
    const int tid  = threadIdx.x;
    const int tx   = tid & 15;          // col group
    const int ty   = tid >> 4;          // row group
    const int brow = (blockIdx.x >> 4) << 6;
    const int bcol = (blockIdx.x & 15) << 6;
    const int ar   = tid >> 2;          // 0..63 (A tile row)
    const int ac   = (tid & 3) << 2;    // 0,4,8,12 (A tile k)
    const int bkr  = tid >> 4;          // 0..15  (B tile k)
    const int bc   = (tid & 15) << 2;   // 0..60  (B tile col)

    float acc[4][4] = {{0.f, 0.f, 0.f, 0.f}, {0.f, 0.f, 0.f, 0.f},
                       {0.f, 0.f, 0.f, 0.f}, {0.f, 0.f, 0.f, 0.f}};

    for (int k0 = 0; k0 < 1024; k0 += 16) {
        float4 av = *(const float4*)&A[(size_t)(brow + ar) * 1024 + k0 + ac];
        float4 bv = *(const float4*)&B[(size_t)(k0 + bkr) * 1024 + bcol + bc];
        __syncthreads();
        As[ac + 0][ar] = av.x;
        As[ac + 1][ar] = av.y;
        As[ac + 2][ar] = av.z;
        As[ac + 3][ar] = av.w;
        *(float4*)&Bs[bkr][bc] = bv;
        __syncthreads();
        #pragma unroll
        for (int k = 0; k < 16; ++k) {
            float4 a4 = *(const float4*)&As[k][ty << 2];
            float4 b4 = *(const float4*)&Bs[k][tx << 2];
            const float* ap = &a4.x;
            const float* bp = &b4.x;
            #pragma unroll
            for (int mi = 0; mi < 4; ++mi)
                #pragma unroll
                for (int ni = 0; ni < 4; ++ni)
                    acc[mi][ni] = fmaf(ap[mi], bp[ni], acc[mi][ni]);
        }
    }
    #pragma unroll
    for (int mi = 0; mi < 4; ++mi) {
        float4 o = make_float4(acc[mi][0], acc[mi][1], acc[mi][2], acc[mi][3]);
        *(float4*)&D[(size_t)(brow + (ty << 2) + mi) * 1024 + bcol + (tx << 2)] = o;
    }
}

// vector @ matrix: y[j] = sum_k v[k] * W[k][j]   (1024x1024)
__global__ void vecmat(const float* __restrict__ v, const float* __restrict__ W,
                       float* __restrict__ y) {
    int j = blockIdx.x * 256 + threadIdx.x;
    float acc = 0.f;
    for (int k = 0; k < 1024; ++k) acc = fmaf(v[k], W[(size_t)k * 1024 + j], acc);
    y[j] = acc;
}

// ---------------------------------------------------------------------------
// K6: out[r] = s3*sum d^2 G[c] + sum (s*d^5 + s3*d^3 + s5*d) C[c]
//            + (s2*u + s*q + s3*p + s4)*beta1p + (s*p + s2)*beta2 + b3
__global__ __launch_bounds__(256) void final_out(const float* __restrict__ C,
                                                 const float* __restrict__ G,
                                                 const int* __restrict__ idx,
                                                 const float* __restrict__ dv,
                                                 const float* __restrict__ beta1p,
                                                 const float* __restrict__ beta2,
                                                 const float* __restrict__ b3,
                                                 float* __restrict__ out) {
    const int r = blockIdx.x;
    __shared__ int   sc[KF];
    __shared__ float sd[KF];
    if (threadIdx.x < KF) {
        int c = idx[r * KF + threadIdx.x];
        sc[threadIdx.x] = c;
        sd[threadIdx.x] = dv[c];
    }
    __syncthreads();

    const float s1 = 1.f / 3.f, s2 = 1.f / 9.f, s3 = 1.f / 27.f,
                s4 = 1.f / 81.f, s5 = 1.f / 243.f;

    float p = 0.f, q = 0.f, sum2 = 0.f;
    #pragma unroll
    for (int i = 0; i < KF; ++i) {
        float dd = sd[i];
        p += dd;
        sum2 += dd * dd;
        q += dd * dd * dd;
    }
    float u   = (float)KF - sum2;           // sum d^2 * cnt
    float g1  = s2 * u + s1 * q + s3 * p + s4;   // beta1' coefficient
    float g2  = s1 * p + s2;                      // beta2 coefficient

    int j = threadIdx.x << 2;
    float4 bb1 = *(const float4*)&beta1p[j];
    float4 bb2 = *(const float4*)&beta2[j];
    float4 b3v = *(const float4*)&b3[j];
    float4 acc;
    acc.x = g1 * bb1.x + g2 * bb2.x + b3v.x;
    acc.y = g1 * bb1.y + g2 * bb2.y + b3v.y;
    acc.z = g1 * bb1.z + g2 * bb2.z + b3v.z;
    acc.w = g1 * bb1.w + g2 * bb2.w + b3v.w;

    #pragma unroll
    for (int i = 0; i < KF; ++i) {
        int   c   = sc[i];
        float dd  = sd[i];
        float dd2 = dd * dd;
        float wG  = s3 * dd2;
        float wC  = dd * (s1 * dd2 * dd2 + s3 * dd2 + s5);
        float4 g  = *(const float4*)&G[(size_t)c * 1024 + j];
        float4 cc = *(const float4*)&C[(size_t)c * 1024 + j];
        acc.x += wG * g.x + wC * cc.x;
        acc.y += wG * g.y + wC * cc.y;
        acc.z += wG * g.z + wC * cc.z;
        acc.w += wG * g.w + wC * cc.w;
    }
    *(float4*)&out[(size_t)r * 1024 + j] = acc;
}

// ---------------------------------------------------------------------------
extern "C" void kernel_launch(void* const* d_in, const int* in_sizes, int n_in,
                              void* d_out, int out_size, void* d_ws, size_t ws_size,
                              hipStream_t stream) {
    const int*   x   = (const int*)d_in[0];
    const float* emb = (const float*)d_in[1];
    const float* Ws  = (const float*)d_in[2];
    const float* bsv = (const float*)d_in[3];
    float* out = (float*)d_out;

    char* ws = (char*)d_ws;
    int*   idx    = (int*)(ws);                         // 256 KB
    int*   cnt    = (int*)(ws + 256 * 1024);            // 4 KB
    float* dv     = (float*)(ws + 260 * 1024);          // 4 KB
    float* bb1    = (float*)(ws + 264 * 1024);          // 4 KB
    float* beta1p = (float*)(ws + 268 * 1024);          // 4 KB
    float* beta2  = (float*)(ws + 272 * 1024);          // 4 KB
    float* Mb     = (float*)(ws + (size_t)(1 << 20) * 1);   // 4 MB
    float* P0     = (float*)(ws + (size_t)(1 << 20) * 5);   // 4 MB (A, then C)
    float* P1     = (float*)(ws + (size_t)(1 << 20) * 9);   // 4 MB (B, then G)

    const float* W1 = Ws;
    const float* W2 = Ws + 1024 * 1024;
    const float* W3 = Ws + 2 * 1024 * 1024;
    const float* b1 = bsv;
    const float* b2 = bsv + 1024;
    const float* b3 = bsv + 2048;

    hipMemsetAsync(cnt, 0, IN_DIM * sizeof(int), stream);
    hipMemsetAsync(Mb, 0, (size_t)IN_DIM * IN_DIM * sizeof(float), stream);

    extract_rows<<<N_ROWS / 4, 256, 0, stream>>>(x, idx, cnt);
    compute_dinv<<<IN_DIM / 256, 256, 0, stream>>>(cnt, dv);
    build_M<<<N_ROWS / 4, 256, 0, stream>>>(idx, Mb);
    scale_M<<<(IN_DIM * IN_DIM) / 256, 256, 0, stream>>>(Mb, dv);

    gemm_f32<<<256, 256, 0, stream>>>(emb, W1, P0);   // A = E @ W1
    gemm_f32<<<256, 256, 0, stream>>>(P0, W2, P1);    // B = A @ W2
    gemm_f32<<<256, 256, 0, stream>>>(P1, W3, P0);    // C = B @ W3   (P0 = C)
    gemm_f32<<<256, 256, 0, stream>>>(Mb, P0, P1);    // G = M~ @ C   (P1 = G)

    vecmat<<<4, 256, 0, stream>>>(b1, W2, bb1);       // bb1 = b1 @ W2
    vecmat<<<4, 256, 0, stream>>>(bb1, W3, beta1p);   // beta1' = bb1 @ W3
    vecmat<<<4, 256, 0, stream>>>(b2, W3, beta2);     // beta2 = b2 @ W3

    final_out<<<N_ROWS, 256, 0, stream>>>(P0, P1, idx, dv, beta1p, beta2, b3, out);
}

// Round 2
// 273.938 us; speedup vs baseline: 1.5456x; 1.5456x over previous
//
#include <hip/hip_runtime.h>

#define N_ROWS 8192
#define IN_DIM 1024
#define EMBD   1024
#define KF     8

// ---------------------------------------------------------------------------
// K1: extract per-row feature indices (ascending) + per-feature counts
__global__ void extract_rows(const int* __restrict__ x,
                             int* __restrict__ idx,
                             int* __restrict__ cnt) {
    const int r    = blockIdx.x * 4 + (threadIdx.x >> 6);
    const int lane = threadIdx.x & 63;
    const int* row = x + (size_t)r * IN_DIM;

    int vals[16];
    #pragma unroll
    for (int j = 0; j < 4; ++j) {
        int4 v = ((const int4*)row)[lane * 4 + j];
        vals[j * 4 + 0] = v.x;
        vals[j * 4 + 1] = v.y;
        vals[j * 4 + 2] = v.z;
        vals[j * 4 + 3] = v.w;
    }
    int c = 0;
    #pragma unroll
    for (int j = 0; j < 16; ++j) c += (vals[j] != 0);

    int s = c;
    #pragma unroll
    for (int o = 1; o < 64; o <<= 1) {
        int t = __shfl_up(s, o, 64);
        if (lane >= o) s += t;
    }
    int pos = s - c;

    #pragma unroll
    for (int j = 0; j < 16; ++j) {
        if (vals[j] != 0) {
            int col = lane * 16 + j;
            if (pos < KF) idx[r * KF + pos] = col;
            pos++;
            atomicAdd(&cnt[col], 1);
        }
    }
}

__global__ void compute_dinv(const int* __restrict__ cnt, float* __restrict__ d) {
    int c = blockIdx.x * 256 + threadIdx.x;
    d[c] = rsqrtf((float)cnt[c] + 1.0f);
}

// co-occurrence counts (integer-exact f32 atomics -> deterministic)
__global__ void build_M(const int* __restrict__ idx, float* __restrict__ M) {
    const int r = blockIdx.x * 4 + (threadIdx.x >> 6);
    const int t = threadIdx.x & 63;
    const int i = t >> 3, j = t & 7;
    int ci = idx[r * KF + i];
    int cj = idx[r * KF + j];
    atomicAdd(&M[ci * IN_DIM + cj], 1.0f);
}

// M~ = M * diag(d)  (scale columns), float4
__global__ void scale_M(float* __restrict__ M, const float* __restrict__ d) {
    int i = (blockIdx.x * 256 + threadIdx.x) << 2;
    float4 m = *(float4*)&M[i];
    float4 dd = *(const float4*)&d[i & (IN_DIM - 1)];
    m.x *= dd.x; m.y *= dd.y; m.z *= dd.z; m.w *= dd.w;
    *(float4*)&M[i] = m;
}

// ---------------------------------------------------------------------------
// f32 GEMM, 64x64 tile, BK=16, 256 threads, 4x4 microtile,
// double-buffered LDS + reg prefetch, K-split 2 (grid 512).
// Dp holds 2 partial [1024][1024] buffers; combine2 adds them.
__global__ __launch_bounds__(256) void gemm_f32_ks2(const float* __restrict__ A,
                                                    const float* __restrict__ B,
                                                    float* __restrict__ Dp) {
    __shared__ float As[2][16][68];
    __shared__ float Bs[2][16][64];
    const int tid  = threadIdx.x;
    const int tx   = tid & 15;
    const int ty   = tid >> 4;
    const int bz   = blockIdx.x >> 8;                  // k-split index
    const int brow = ((blockIdx.x >> 4) & 15) << 6;
    const int bcol = (blockIdx.x & 15) << 6;
    const int ar   = tid >> 2;
    const int ac   = (tid & 3) << 2;
    const int bkr  = tid >> 4;
    const int bc   = (tid & 15) << 2;
    const int kbeg = bz << 9;                          // 0 or 512

    const float* Aro = A + (size_t)(brow + ar) * 1024 + kbeg + ac;
    const float* Bro = B + (size_t)(kbeg + bkr) * 1024 + bcol + bc;

    // prologue: tile 0 -> LDS[0]
    {
        float4 av = *(const float4*)Aro;
        float4 bv = *(const float4*)Bro;
        As[0][ac + 0][ar] = av.x;
        As[0][ac + 1][ar] = av.y;
        As[0][ac + 2][ar] = av.z;
        As[0][ac + 3][ar] = av.w;
        *(float4*)&Bs[0][bkr][bc] = bv;
    }
    __syncthreads();

    float acc[4][4] = {{0.f,0.f,0.f,0.f},{0.f,0.f,0.f,0.f},
                       {0.f,0.f,0.f,0.f},{0.f,0.f,0.f,0.f}};
    int cur = 0;
    for (int kt = 1; kt < 32; ++kt) {
        // prefetch next tile into regs (latency hidden under compute below)
        float4 av = *(const float4*)(Aro + kt * 16);
        float4 bv = *(const float4*)(Bro + (size_t)kt * 16 * 1024);

        #pragma unroll
        for (int k = 0; k < 16; ++k) {
            float4 a4 = *(const float4*)&As[cur][k][ty << 2];
            float4 b4 = *(const float4*)&Bs[cur][k][tx << 2];
            const float* ap = &a4.x;
            const float* bp = &b4.x;
            #pragma unroll
            for (int mi = 0; mi < 4; ++mi)
                #pragma unroll
                for (int ni = 0; ni < 4; ++ni)
                    acc[mi][ni] = fmaf(ap[mi], bp[ni], acc[mi][ni]);
        }
        // write prefetched tile to the other buffer (no hazard with reads above)
        int nxt = cur ^ 1;
        As[nxt][ac + 0][ar] = av.x;
        As[nxt][ac + 1][ar] = av.y;
        As[nxt][ac + 2][ar] = av.z;
        As[nxt][ac + 3][ar] = av.w;
        *(float4*)&Bs[nxt][bkr][bc] = bv;
        __syncthreads();
        cur = nxt;
    }
    #pragma unroll
    for (int k = 0; k < 16; ++k) {
        float4 a4 = *(const float4*)&As[cur][k][ty << 2];
        float4 b4 = *(const float4*)&Bs[cur][k][tx << 2];
        const float* ap = &a4.x;
        const float* bp = &b4.x;
        #pragma unroll
        for (int mi = 0; mi < 4; ++mi)
            #pragma unroll
            for (int ni = 0; ni < 4; ++ni)
                acc[mi][ni] = fmaf(ap[mi], bp[ni], acc[mi][ni]);
    }

    float* Dt = Dp + ((size_t)bz << 20);
    #pragma unroll
    for (int mi = 0; mi < 4; ++mi) {
        float4 o = make_float4(acc[mi][0], acc[mi][1], acc[mi][2], acc[mi][3]);
        *(float4*)&Dt[(size_t)(brow + (ty << 2) + mi) * 1024 + bcol + (tx << 2)] = o;
    }
}

__global__ void combine2(const float* __restrict__ Pp, float* __restrict__ D) {
    int i = (blockIdx.x * 256 + threadIdx.x) << 2;
    float4 a = *(const float4*)&Pp[i];
    float4 b = *(const float4*)&Pp[(1 << 20) + i];
    a.x += b.x; a.y += b.y; a.z += b.z; a.w += b.w;
    *(float4*)&D[i] = a;
}

// vector @ matrix with k-sliced threads: grid 32, block 256 = 32 j x 8 kg
__global__ __launch_bounds__(256) void vecmat2(const float* __restrict__ v,
                                               const float* __restrict__ W,
                                               float* __restrict__ y) {
    __shared__ float red[8][33];
    const int jl = threadIdx.x & 31;
    const int kg = threadIdx.x >> 5;
    const int j  = blockIdx.x * 32 + jl;
    float acc = 0.f;
    const int k0 = kg << 7;
    for (int k = k0; k < k0 + 128; ++k)
        acc = fmaf(v[k], W[(size_t)k * 1024 + j], acc);
    red[kg][jl] = acc;
    __syncthreads();
    if (kg == 0) {
        float s = 0.f;
        #pragma unroll
        for (int g = 0; g < 8; ++g) s += red[g][jl];
        y[j] = s;
    }
}

// ---------------------------------------------------------------------------
__global__ __launch_bounds__(256) void final_out(const float* __restrict__ C,
                                                 const float* __restrict__ G,
                                                 const int* __restrict__ idx,
                                                 const float* __restrict__ dv,
                                                 const float* __restrict__ beta1p,
                                                 const float* __restrict__ beta2,
                                                 const float* __restrict__ b3,
                                                 float* __restrict__ out) {
    const int r = blockIdx.x;
    __shared__ int   sc[KF];
    __shared__ float sd[KF];
    if (threadIdx.x < KF) {
        int c = idx[r * KF + threadIdx.x];
        sc[threadIdx.x] = c;
        sd[threadIdx.x] = dv[c];
    }
    __syncthreads();

    const float s1 = 1.f / 3.f, s2 = 1.f / 9.f, s3 = 1.f / 27.f,
                s4 = 1.f / 81.f, s5 = 1.f / 243.f;

    float p = 0.f, q = 0.f, sum2 = 0.f;
    #pragma unroll
    for (int i = 0; i < KF; ++i) {
        float dd = sd[i];
        p += dd;
        sum2 += dd * dd;
        q += dd * dd * dd;
    }
    float u  = (float)KF - sum2;
    float g1 = s2 * u + s1 * q + s3 * p + s4;
    float g2 = s1 * p + s2;

    int j = threadIdx.x << 2;
    float4 bb1 = *(const float4*)&beta1p[j];
    float4 bb2 = *(const float4*)&beta2[j];
    float4 b3v = *(const float4*)&b3[j];
    float4 acc;
    acc.x = g1 * bb1.x + g2 * bb2.x + b3v.x;
    acc.y = g1 * bb1.y + g2 * bb2.y + b3v.y;
    acc.z = g1 * bb1.z + g2 * bb2.z + b3v.z;
    acc.w = g1 * bb1.w + g2 * bb2.w + b3v.w;

    #pragma unroll
    for (int i = 0; i < KF; ++i) {
        int   c   = sc[i];
        float dd  = sd[i];
        float dd2 = dd * dd;
        float wG  = s3 * dd2;
        float wC  = dd * (s1 * dd2 * dd2 + s3 * dd2 + s5);
        float4 g  = *(const float4*)&G[(size_t)c * 1024 + j];
        float4 cc = *(const float4*)&C[(size_t)c * 1024 + j];
        acc.x += wG * g.x + wC * cc.x;
        acc.y += wG * g.y + wC * cc.y;
        acc.z += wG * g.z + wC * cc.z;
        acc.w += wG * g.w + wC * cc.w;
    }
    *(float4*)&out[(size_t)r * 1024 + j] = acc;
}

// ---------------------------------------------------------------------------
extern "C" void kernel_launch(void* const* d_in, const int* in_sizes, int n_in,
                              void* d_out, int out_size, void* d_ws, size_t ws_size,
                              hipStream_t stream) {
    const int*   x   = (const int*)d_in[0];
    const float* emb = (const float*)d_in[1];
    const float* Ws  = (const float*)d_in[2];
    const float* bsv = (const float*)d_in[3];
    float* out = (float*)d_out;

    char* ws = (char*)d_ws;
    int*   idx    = (int*)(ws);                          // 256 KB
    int*   cnt    = (int*)(ws + 256 * 1024);             // 4 KB
    float* dv     = (float*)(ws + 260 * 1024);           // 4 KB
    float* bb1    = (float*)(ws + 264 * 1024);           // 4 KB
    float* beta1p = (float*)(ws + 268 * 1024);           // 4 KB
    float* beta2  = (float*)(ws + 272 * 1024);           // 4 KB
    float* Mb     = (float*)(ws + (size_t)(1 << 20) * 1);    // 4 MB
    float* P0     = (float*)(ws + (size_t)(1 << 20) * 5);    // 4 MB
    float* P1     = (float*)(ws + (size_t)(1 << 20) * 9);    // 4 MB
    float* Pp     = (float*)(ws + (size_t)(1 << 20) * 13);   // 8 MB (k-split partials)

    const float* W1 = Ws;
    const float* W2 = Ws + 1024 * 1024;
    const float* W3 = Ws + 2 * 1024 * 1024;
    const float* b1 = bsv;
    const float* b2 = bsv + 1024;
    const float* b3 = bsv + 2048;

    hipMemsetAsync(cnt, 0, IN_DIM * sizeof(int), stream);
    hipMemsetAsync(Mb, 0, (size_t)IN_DIM * IN_DIM * sizeof(float), stream);

    extract_rows<<<N_ROWS / 4, 256, 0, stream>>>(x, idx, cnt);
    compute_dinv<<<IN_DIM / 256, 256, 0, stream>>>(cnt, dv);
    build_M<<<N_ROWS / 4, 256, 0, stream>>>(idx, Mb);
    scale_M<<<(IN_DIM * IN_DIM) / 1024, 256, 0, stream>>>(Mb, dv);

    // bias chain (independent of GEMM chain)
    vecmat2<<<32, 256, 0, stream>>>(b1, W2, bb1);
    vecmat2<<<32, 256, 0, stream>>>(bb1, W3, beta1p);
    vecmat2<<<32, 256, 0, stream>>>(b2, W3, beta2);

    gemm_f32_ks2<<<512, 256, 0, stream>>>(emb, W1, Pp);
    combine2<<<1024, 256, 0, stream>>>(Pp, P0);          // A = E @ W1
    gemm_f32_ks2<<<512, 256, 0, stream>>>(P0, W2, Pp);
    combine2<<<1024, 256, 0, stream>>>(Pp, P1);          // B = A @ W2
    gemm_f32_ks2<<<512, 256, 0, stream>>>(P1, W3, Pp);
    combine2<<<1024, 256, 0, stream>>>(Pp, P0);          // C = B @ W3
    gemm_f32_ks2<<<512, 256, 0, stream>>>(Mb, P0, Pp);
    combine2<<<1024, 256, 0, stream>>>(Pp, P1);          // G = M~ @ C

    final_out<<<N_ROWS, 256, 0, stream>>>(P0, P1, idx, dv, beta1p, beta2, b3, out);
}

// Round 3
// 268.477 us; speedup vs baseline: 1.5770x; 1.0203x over previous
//
#include <hip/hip_runtime.h>

#define N_ROWS 8192
#define IN_DIM 1024
#define KF     8
#define PSLICE (1088 * 1024)   // k-split partial slice stride (floats)

// ---------------------------------------------------------------------------
// K1: extract per-row feature indices (ascending) + per-feature counts
__global__ void extract_rows(const int* __restrict__ x,
                             int* __restrict__ idx,
                             int* __restrict__ cnt) {
    const int r    = blockIdx.x * 4 + (threadIdx.x >> 6);
    const int lane = threadIdx.x & 63;
    const int* row = x + (size_t)r * IN_DIM;

    int vals[16];
    #pragma unroll
    for (int j = 0; j < 4; ++j) {
        int4 v = ((const int4*)row)[lane * 4 + j];
        vals[j * 4 + 0] = v.x;
        vals[j * 4 + 1] = v.y;
        vals[j * 4 + 2] = v.z;
        vals[j * 4 + 3] = v.w;
    }
    int c = 0;
    #pragma unroll
    for (int j = 0; j < 16; ++j) c += (vals[j] != 0);

    int s = c;
    #pragma unroll
    for (int o = 1; o < 64; o <<= 1) {
        int t = __shfl_up(s, o, 64);
        if (lane >= o) s += t;
    }
    int pos = s - c;

    #pragma unroll
    for (int j = 0; j < 16; ++j) {
        if (vals[j] != 0) {
            int col = lane * 16 + j;
            if (pos < KF) idx[r * KF + pos] = col;
            pos++;
            atomicAdd(&cnt[col], 1);
        }
    }
}

// dinv + per-feature H-combine weights
__global__ void compute_w(const int* __restrict__ cnt, float* __restrict__ dv,
                          float* __restrict__ wGv, float* __restrict__ wCv) {
    const float s1 = 1.f / 3.f, s3 = 1.f / 27.f, s5 = 1.f / 243.f;
    int c = blockIdx.x * 256 + threadIdx.x;
    float d  = rsqrtf((float)cnt[c] + 1.0f);
    float d2 = d * d;
    dv[c]  = d;
    wGv[c] = s3 * d2;
    wCv[c] = d * (s1 * d2 * d2 + s3 * d2 + s5);
}

// co-occurrence counts (integer-exact f32 atomics -> deterministic)
__global__ void build_M(const int* __restrict__ idx, float* __restrict__ M) {
    const int r = blockIdx.x * 4 + (threadIdx.x >> 6);
    const int t = threadIdx.x & 63;
    const int i = t >> 3, j = t & 7;
    int ci = idx[r * KF + i];
    int cj = idx[r * KF + j];
    atomicAdd(&M[ci * IN_DIM + cj], 1.0f);
}

// M~ = M * diag(d)
__global__ void scale_M(float* __restrict__ M, const float* __restrict__ d) {
    int i = (blockIdx.x * 256 + threadIdx.x) << 2;
    float4 m = *(float4*)&M[i];
    float4 dd = *(const float4*)&d[i & (IN_DIM - 1)];
    m.x *= dd.x; m.y *= dd.y; m.z *= dd.z; m.w *= dd.w;
    *(float4*)&M[i] = m;
}

// ---------------------------------------------------------------------------
// f32 GEMM, 64x64 tile, BK=16, 256 threads, 4x4 microtile, dbuf LDS + reg
// prefetch, K-split 4. grid = dim3(16, RT, 4). Rows >= Mv contribute zeros.
__global__ __launch_bounds__(256, 4) void gemm_f32_ks4(const float* __restrict__ A,
                                                       const float* __restrict__ B,
                                                       float* __restrict__ Dp,
                                                       int Mv) {
    __shared__ float As[2][16][68];
    __shared__ float Bs[2][16][64];
    const int tid  = threadIdx.x;
    const int tx   = tid & 15;
    const int ty   = tid >> 4;
    const int brow = blockIdx.y << 6;
    const int bcol = blockIdx.x << 6;
    const int bz   = blockIdx.z;
    const int ar   = tid >> 2;
    const int ac   = (tid & 3) << 2;
    const int bkr  = tid >> 4;
    const int bc   = (tid & 15) << 2;
    const int kbeg = bz << 8;            // 256 per split

    const int arow   = brow + ar;
    const float msk  = (arow < Mv) ? 1.f : 0.f;
    const int arowc  = (arow < Mv) ? arow : (Mv - 1);
    const float* Aro = A + (size_t)arowc * 1024 + kbeg + ac;
    const float* Bro = B + (size_t)(kbeg + bkr) * 1024 + bcol + bc;

    {
        float4 av = *(const float4*)Aro;
        float4 bv = *(const float4*)Bro;
        As[0][ac + 0][ar] = av.x * msk;
        As[0][ac + 1][ar] = av.y * msk;
        As[0][ac + 2][ar] = av.z * msk;
        As[0][ac + 3][ar] = av.w * msk;
        *(float4*)&Bs[0][bkr][bc] = bv;
    }
    __syncthreads();

    float acc[4][4] = {{0.f,0.f,0.f,0.f},{0.f,0.f,0.f,0.f},
                       {0.f,0.f,0.f,0.f},{0.f,0.f,0.f,0.f}};
    int cur = 0;
    for (int kt = 1; kt < 16; ++kt) {
        float4 av = *(const float4*)(Aro + kt * 16);
        float4 bv = *(const float4*)(Bro + (size_t)kt * 16 * 1024);

        #pragma unroll
        for (int k = 0; k < 16; ++k) {
            float4 a4 = *(const float4*)&As[cur][k][ty << 2];
            float4 b4 = *(const float4*)&Bs[cur][k][tx << 2];
            const float* ap = &a4.x;
            const float* bp = &b4.x;
            #pragma unroll
            for (int mi = 0; mi < 4; ++mi)
                #pragma unroll
                for (int ni = 0; ni < 4; ++ni)
                    acc[mi][ni] = fmaf(ap[mi], bp[ni], acc[mi][ni]);
        }
        int nxt = cur ^ 1;
        As[nxt][ac + 0][ar] = av.x * msk;
        As[nxt][ac + 1][ar] = av.y * msk;
        As[nxt][ac + 2][ar] = av.z * msk;
        As[nxt][ac + 3][ar] = av.w * msk;
        *(float4*)&Bs[nxt][bkr][bc] = bv;
        __syncthreads();
        cur = nxt;
    }
    #pragma unroll
    for (int k = 0; k < 16; ++k) {
        float4 a4 = *(const float4*)&As[cur][k][ty << 2];
        float4 b4 = *(const float4*)&Bs[cur][k][tx << 2];
        const float* ap = &a4.x;
        const float* bp = &b4.x;
        #pragma unroll
        for (int mi = 0; mi < 4; ++mi)
            #pragma unroll
            for (int ni = 0; ni < 4; ++ni)
                acc[mi][ni] = fmaf(ap[mi], bp[ni], acc[mi][ni]);
    }

    float* Dt = Dp + (size_t)bz * PSLICE;
    #pragma unroll
    for (int mi = 0; mi < 4; ++mi) {
        float4 o = make_float4(acc[mi][0], acc[mi][1], acc[mi][2], acc[mi][3]);
        *(float4*)&Dt[(size_t)(brow + (ty << 2) + mi) * 1024 + bcol + (tx << 2)] = o;
    }
}

// sum 4 k-split partials; grid = nrows (one row per block)
__global__ void combine4(const float* __restrict__ Pp, float* __restrict__ D) {
    size_t i = ((size_t)blockIdx.x * 256 + threadIdx.x) << 2;
    float4 a = *(const float4*)&Pp[i];
    float4 b = *(const float4*)&Pp[PSLICE + i];
    float4 c = *(const float4*)&Pp[2 * (size_t)PSLICE + i];
    float4 d = *(const float4*)&Pp[3 * (size_t)PSLICE + i];
    a.x += b.x + c.x + d.x;
    a.y += b.y + c.y + d.y;
    a.z += b.z + c.z + d.z;
    a.w += b.w + c.w + d.w;
    *(float4*)&D[i] = a;
}

// sum 4 partials of G and fold with C into H = wG*G + wC*C; grid = 1024
__global__ void combineH(const float* __restrict__ Pp, const float* __restrict__ C,
                         const float* __restrict__ wGv, const float* __restrict__ wCv,
                         float* __restrict__ H) {
    const int r = blockIdx.x;
    size_t i = (size_t)r * 1024 + (threadIdx.x << 2);
    float4 a = *(const float4*)&Pp[i];
    float4 b = *(const float4*)&Pp[PSLICE + i];
    float4 c = *(const float4*)&Pp[2 * (size_t)PSLICE + i];
    float4 d = *(const float4*)&Pp[3 * (size_t)PSLICE + i];
    float4 c4 = *(const float4*)&C[i];
    float wg = wGv[r], wc = wCv[r];
    float4 h;
    h.x = wg * (a.x + b.x + c.x + d.x) + wc * c4.x;
    h.y = wg * (a.y + b.y + c.y + d.y) + wc * c4.y;
    h.z = wg * (a.z + b.z + c.z + d.z) + wc * c4.z;
    h.w = wg * (a.w + b.w + c.w + d.w) + wc * c4.w;
    *(float4*)&H[i] = h;
}

// copy 1024 floats (append bias rows)
__global__ void copy_row(const float* __restrict__ src, float* __restrict__ dst) {
    int j = threadIdx.x << 2;
    *(float4*)&dst[j] = *(const float4*)&src[j];
}

// ---------------------------------------------------------------------------
// out[r] = sum_i H[c_i] + g1*beta1p + g2*beta2 + b3
__global__ __launch_bounds__(256) void final_out(const float* __restrict__ H,
                                                 const int* __restrict__ idx,
                                                 const float* __restrict__ dv,
                                                 const float* __restrict__ beta1p,
                                                 const float* __restrict__ beta2,
                                                 const float* __restrict__ b3,
                                                 float* __restrict__ out) {
    const int r = blockIdx.x;
    __shared__ int   sc[KF];
    __shared__ float sd[KF];
    if (threadIdx.x < KF) {
        int c = idx[r * KF + threadIdx.x];
        sc[threadIdx.x] = c;
        sd[threadIdx.x] = dv[c];
    }
    __syncthreads();

    const float s1 = 1.f / 3.f, s2 = 1.f / 9.f, s3 = 1.f / 27.f, s4 = 1.f / 81.f;

    float p = 0.f, q = 0.f, sum2 = 0.f;
    #pragma unroll
    for (int i = 0; i < KF; ++i) {
        float dd = sd[i];
        p += dd;
        sum2 += dd * dd;
        q += dd * dd * dd;
    }
    float u  = (float)KF - sum2;
    float g1 = s2 * u + s1 * q + s3 * p + s4;
    float g2 = s1 * p + s2;

    int j = threadIdx.x << 2;
    float4 bb1 = *(const float4*)&beta1p[j];
    float4 bb2 = *(const float4*)&beta2[j];
    float4 b3v = *(const float4*)&b3[j];
    float4 acc;
    acc.x = g1 * bb1.x + g2 * bb2.x + b3v.x;
    acc.y = g1 * bb1.y + g2 * bb2.y + b3v.y;
    acc.z = g1 * bb1.z + g2 * bb2.z + b3v.z;
    acc.w = g1 * bb1.w + g2 * bb2.w + b3v.w;

    #pragma unroll
    for (int i = 0; i < KF; ++i) {
        float4 h = *(const float4*)&H[(size_t)sc[i] * 1024 + j];
        acc.x += h.x;
        acc.y += h.y;
        acc.z += h.z;
        acc.w += h.w;
    }
    *(float4*)&out[(size_t)r * 1024 + j] = acc;
}

// ---------------------------------------------------------------------------
extern "C" void kernel_launch(void* const* d_in, const int* in_sizes, int n_in,
                              void* d_out, int out_size, void* d_ws, size_t ws_size,
                              hipStream_t stream) {
    const int*   x   = (const int*)d_in[0];
    const float* emb = (const float*)d_in[1];
    const float* Ws  = (const float*)d_in[2];
    const float* bsv = (const float*)d_in[3];
    float* out = (float*)d_out;

    char* ws = (char*)d_ws;
    int*   idx  = (int*)(ws);                            // 256 KB
    int*   cnt  = (int*)(ws + 256 * 1024);               // 4 KB
    float* dv   = (float*)(ws + 264 * 1024);             // 4 KB
    float* wGv  = (float*)(ws + 272 * 1024);             // 4 KB
    float* wCv  = (float*)(ws + 280 * 1024);             // 4 KB
    float* Mb   = (float*)(ws + (size_t)(1 << 20) * 1);  // 4 MB
    float* P0   = (float*)(ws + (size_t)(1 << 20) * 5);  // 4.46 MB (1088 rows)
    float* P1   = (float*)(ws + (size_t)(1 << 20) * 10); // 4.46 MB
    float* H    = (float*)(ws + (size_t)(1 << 20) * 15); // 4 MB
    float* Pp   = (float*)(ws + (size_t)(1 << 20) * 20); // 17.8 MB (4 slices)

    const float* W1 = Ws;
    const float* W2 = Ws + 1024 * 1024;
    const float* W3 = Ws + 2 * 1024 * 1024;
    const float* b1 = bsv;
    const float* b2 = bsv + 1024;
    const float* b3 = bsv + 2048;

    hipMemsetAsync(cnt, 0, IN_DIM * sizeof(int), stream);
    hipMemsetAsync(Mb, 0, (size_t)IN_DIM * IN_DIM * sizeof(float), stream);

    extract_rows<<<N_ROWS / 4, 256, 0, stream>>>(x, idx, cnt);
    compute_w<<<IN_DIM / 256, 256, 0, stream>>>(cnt, dv, wGv, wCv);
    build_M<<<N_ROWS / 4, 256, 0, stream>>>(idx, Mb);
    scale_M<<<(IN_DIM * IN_DIM) / 1024, 256, 0, stream>>>(Mb, dv);

    // chain with bias rows folded in:
    gemm_f32_ks4<<<dim3(16, 16, 4), 256, 0, stream>>>(emb, W1, Pp, 1024);
    combine4<<<1024, 256, 0, stream>>>(Pp, P0);            // A = E@W1
    copy_row<<<1, 256, 0, stream>>>(b1, P0 + 1024 * 1024); // row 1024 = b1

    gemm_f32_ks4<<<dim3(16, 17, 4), 256, 0, stream>>>(P0, W2, Pp, 1025);
    combine4<<<1025, 256, 0, stream>>>(Pp, P1);            // B_ext
    copy_row<<<1, 256, 0, stream>>>(b2, P1 + 1025 * 1024); // row 1025 = b2

    gemm_f32_ks4<<<dim3(16, 17, 4), 256, 0, stream>>>(P1, W3, Pp, 1026);
    combine4<<<1026, 256, 0, stream>>>(Pp, P0);            // C_ext (+beta1p,beta2)

    gemm_f32_ks4<<<dim3(16, 16, 4), 256, 0, stream>>>(Mb, P0, Pp, 1024);
    combineH<<<1024, 256, 0, stream>>>(Pp, P0, wGv, wCv, H);

    final_out<<<N_ROWS, 256, 0, stream>>>(H, idx, dv,
                                          P0 + 1024 * 1024, P0 + 1025 * 1024,
                                          b3, out);
}

// Round 5
// 171.370 us; speedup vs baseline: 2.4707x; 1.5667x over previous
//
#include <hip/hip_runtime.h>

#define N_ROWS 8192
#define IN_DIM 1024
#define KF     8

typedef _Float16 half8 __attribute__((ext_vector_type(8)));
typedef _Float16 half4 __attribute__((ext_vector_type(4)));
typedef float    floatx4 __attribute__((ext_vector_type(4)));

__device__ __forceinline__ half8 ld_half8(const _Float16* p) {
    int4 t = *(const int4*)p;
    return __builtin_bit_cast(half8, t);
}
__device__ __forceinline__ void fsplit(float v, _Float16& h, _Float16& l) {
    _Float16 x = (_Float16)v;
    h = x;
    l = (_Float16)((v - (float)x) * 2048.0f);
}

// ---------------------------------------------------------------------------
__global__ void extract_rows(const int* __restrict__ x,
                             int* __restrict__ idx,
                             int* __restrict__ cnt) {
    const int r    = blockIdx.x * 4 + (threadIdx.x >> 6);
    const int lane = threadIdx.x & 63;
    const int* row = x + (size_t)r * IN_DIM;

    int vals[16];
    #pragma unroll
    for (int j = 0; j < 4; ++j) {
        int4 v = ((const int4*)row)[lane * 4 + j];
        vals[j * 4 + 0] = v.x;
        vals[j * 4 + 1] = v.y;
        vals[j * 4 + 2] = v.z;
        vals[j * 4 + 3] = v.w;
    }
    int c = 0;
    #pragma unroll
    for (int j = 0; j < 16; ++j) c += (vals[j] != 0);

    int s = c;
    #pragma unroll
    for (int o = 1; o < 64; o <<= 1) {
        int t = __shfl_up(s, o, 64);
        if (lane >= o) s += t;
    }
    int pos = s - c;

    #pragma unroll
    for (int j = 0; j < 16; ++j) {
        if (vals[j] != 0) {
            int col = lane * 16 + j;
            if (pos < KF) idx[r * KF + pos] = col;
            pos++;
            atomicAdd(&cnt[col], 1);
        }
    }
}

__global__ void compute_w(const int* __restrict__ cnt, float* __restrict__ dv,
                          float* __restrict__ wGv, float* __restrict__ wCv) {
    const float s1 = 1.f / 3.f, s3 = 1.f / 27.f, s5 = 1.f / 243.f;
    int c = blockIdx.x * 256 + threadIdx.x;
    float d  = rsqrtf((float)cnt[c] + 1.0f);
    float d2 = d * d;
    dv[c]  = d;
    wGv[c] = s3 * d2;
    wCv[c] = d * (s1 * d2 * d2 + s3 * d2 + s5);
}

// co-occurrence counts (integer-exact f32 atomics -> deterministic)
__global__ void build_M(const int* __restrict__ idx, float* __restrict__ M) {
    const int r = blockIdx.x * 4 + (threadIdx.x >> 6);
    const int t = threadIdx.x & 63;
    const int i = t >> 3, j = t & 7;
    int ci = idx[r * KF + i];
    int cj = idx[r * KF + j];
    atomicAdd(&M[ci * IN_DIM + cj], 1.0f);
}

// M'[i][j] = wG[i]*Mcnt[i][j]*dv[j] + (i==j)*wC[i], split to f16 hi/lo
__global__ void scale_splitM(const float* __restrict__ Mc, const float* __restrict__ dv,
                             const float* __restrict__ wGv, const float* __restrict__ wCv,
                             _Float16* __restrict__ Mh, _Float16* __restrict__ Ml) {
    size_t i = ((size_t)blockIdx.x * 256 + threadIdx.x) << 2;
    int row = (int)(i >> 10);
    int cb  = (int)(i & 1023);
    float wg = wGv[row];
    float4 m  = *(const float4*)&Mc[i];
    float4 dd = *(const float4*)&dv[cb];
    float v[4] = {m.x * dd.x * wg, m.y * dd.y * wg, m.z * dd.z * wg, m.w * dd.w * wg};
    #pragma unroll
    for (int j = 0; j < 4; ++j)
        if (cb + j == row) v[j] += wCv[row];
    half4 h, l;
    #pragma unroll
    for (int j = 0; j < 4; ++j) { _Float16 hh, ll; fsplit(v[j], hh, ll); h[j] = hh; l[j] = ll; }
    *(int2*)&Mh[i] = __builtin_bit_cast(int2, h);
    *(int2*)&Ml[i] = __builtin_bit_cast(int2, l);
}

// natural split f32 -> f16 hi/lo (E and W2 via blockIdx.y)
__global__ void split_nat(const float* __restrict__ S0, const float* __restrict__ S1,
                          _Float16* __restrict__ H0, _Float16* __restrict__ L0,
                          _Float16* __restrict__ H1, _Float16* __restrict__ L1) {
    const float* S = blockIdx.y ? S1 : S0;
    _Float16* Hp = blockIdx.y ? H1 : H0;
    _Float16* Lp = blockIdx.y ? L1 : L0;
    size_t i = ((size_t)blockIdx.x * 256 + threadIdx.x) << 2;
    float4 v = *(const float4*)&S[i];
    float vv[4] = {v.x, v.y, v.z, v.w};
    half4 h, l;
    #pragma unroll
    for (int j = 0; j < 4; ++j) { _Float16 hh, ll; fsplit(vv[j], hh, ll); h[j] = hh; l[j] = ll; }
    *(int2*)&Hp[i] = __builtin_bit_cast(int2, h);
    *(int2*)&Lp[i] = __builtin_bit_cast(int2, l);
}

// transposed split: O[n][k] = split(S[k][n])  (W1 and W3 via blockIdx.z)
__global__ __launch_bounds__(256) void transp_split(
        const float* __restrict__ S0, const float* __restrict__ S1,
        _Float16* __restrict__ H0, _Float16* __restrict__ L0,
        _Float16* __restrict__ H1, _Float16* __restrict__ L1) {
    const float* S = blockIdx.z ? S1 : S0;
    _Float16* Hp = blockIdx.z ? H1 : H0;
    _Float16* Lp = blockIdx.z ? L1 : L0;
    __shared__ float sh[64][65];
    const int r0 = blockIdx.y << 6, c0 = blockIdx.x << 6;
    #pragma unroll
    for (int it = 0; it < 4; ++it) {
        int r = (threadIdx.x >> 4) + (it << 4);
        int c = (threadIdx.x & 15) << 2;
        float4 v = *(const float4*)&S[(size_t)(r0 + r) * 1024 + c0 + c];
        sh[r][c] = v.x; sh[r][c + 1] = v.y; sh[r][c + 2] = v.z; sh[r][c + 3] = v.w;
    }
    __syncthreads();
    int nl = threadIdx.x >> 2;
    #pragma unroll
    for (int cc = 0; cc < 2; ++cc) {
        int kq = ((threadIdx.x & 3) << 4) + (cc << 3);
        half8 h, l;
        #pragma unroll
        for (int j = 0; j < 8; ++j) {
            _Float16 hh, ll;
            fsplit(sh[kq + j][nl], hh, ll);
            h[j] = hh; l[j] = ll;
        }
        *(int4*)&Hp[(size_t)(c0 + nl) * 1024 + r0 + kq] = __builtin_bit_cast(int4, h);
        *(int4*)&Lp[(size_t)(c0 + nl) * 1024 + r0 + kq] = __builtin_bit_cast(int4, l);
    }
}

// ---------------------------------------------------------------------------
// split-f16 MFMA GEMM: D[1024x1024] = A @ B, A given split natural (h/l),
// B given split TRANSPOSED ([n][k]).  64x64 tile, 4 waves, 2x2 frags of
// 16x16x32 per wave, 3 MFMA per frag (hh, h*l, l*h), dbuf LDS.
// Epilogue: optional f32 / natural-split / transposed-split outputs.
__global__ __launch_bounds__(256) void gemm_split(
    const _Float16* __restrict__ Agh, const _Float16* __restrict__ Agl,
    const _Float16* __restrict__ Bgh, const _Float16* __restrict__ Bgl,
    float* __restrict__ Df,
    _Float16* __restrict__ Dnh, _Float16* __restrict__ Dnl,
    _Float16* __restrict__ Dth, _Float16* __restrict__ Dtl)
{
    __shared__ _Float16 Ash[2][64][40];
    __shared__ _Float16 Asl[2][64][40];
    __shared__ _Float16 Bsh[2][64][40];
    __shared__ _Float16 Bsl[2][64][40];

    const int tid  = threadIdx.x;
    const int lane = tid & 63;
    const int w    = tid >> 6;
    const int mr   = (w >> 1) << 5;
    const int nr   = (w & 1) << 5;
    const int brow = blockIdx.y << 6;
    const int bcol = blockIdx.x << 6;

    const int sm = tid >> 2;           // staged row 0..63
    const int sk = (tid & 3) << 3;     // staged k offset 0,8,16,24

    const _Float16* pAh = Agh + (size_t)(brow + sm) * 1024 + sk;
    const _Float16* pAl = Agl + (size_t)(brow + sm) * 1024 + sk;
    const _Float16* pBh = Bgh + (size_t)(bcol + sm) * 1024 + sk;
    const _Float16* pBl = Bgl + (size_t)(bcol + sm) * 1024 + sk;

    const int fr = lane & 15;
    const int fk = (lane >> 4) << 3;   // per-lane k offset within 32

    floatx4 acc0[2][2] = {};
    floatx4 acc1[2][2] = {};

    int4 ra, rl, rb, rbl;
    ra  = *(const int4*)pAh;
    rl  = *(const int4*)pAl;
    rb  = *(const int4*)pBh;
    rbl = *(const int4*)pBl;
    *(int4*)&Ash[0][sm][sk] = ra;
    *(int4*)&Asl[0][sm][sk] = rl;
    *(int4*)&Bsh[0][sm][sk] = rb;
    *(int4*)&Bsl[0][sm][sk] = rbl;
    __syncthreads();

    int cur = 0;
    for (int kt = 1; kt <= 32; ++kt) {
        if (kt < 32) {
            size_t o = (size_t)kt * 32;
            ra  = *(const int4*)(pAh + o);
            rl  = *(const int4*)(pAl + o);
            rb  = *(const int4*)(pBh + o);
            rbl = *(const int4*)(pBl + o);
        }
        half8 afh[2], afl[2], bfh[2], bfl[2];
        #pragma unroll
        for (int f = 0; f < 2; ++f) {
            afh[f] = ld_half8(&Ash[cur][mr + (f << 4) + fr][fk]);
            afl[f] = ld_half8(&Asl[cur][mr + (f << 4) + fr][fk]);
            bfh[f] = ld_half8(&Bsh[cur][nr + (f << 4) + fr][fk]);
            bfl[f] = ld_half8(&Bsl[cur][nr + (f << 4) + fr][fk]);
        }
        #pragma unroll
        for (int fi = 0; fi < 2; ++fi)
            #pragma unroll
            for (int fj = 0; fj < 2; ++fj)
                acc0[fi][fj] = __builtin_amdgcn_mfma_f32_16x16x32_f16(afh[fi], bfh[fj], acc0[fi][fj], 0, 0, 0);
        #pragma unroll
        for (int fi = 0; fi < 2; ++fi)
            #pragma unroll
            for (int fj = 0; fj < 2; ++fj)
                acc1[fi][fj] = __builtin_amdgcn_mfma_f32_16x16x32_f16(afh[fi], bfl[fj], acc1[fi][fj], 0, 0, 0);
        #pragma unroll
        for (int fi = 0; fi < 2; ++fi)
            #pragma unroll
            for (int fj = 0; fj < 2; ++fj)
                acc1[fi][fj] = __builtin_amdgcn_mfma_f32_16x16x32_f16(afl[fi], bfh[fj], acc1[fi][fj], 0, 0, 0);

        if (kt < 32) {
            int nb = cur ^ 1;
            *(int4*)&Ash[nb][sm][sk] = ra;
            *(int4*)&Asl[nb][sm][sk] = rl;
            *(int4*)&Bsh[nb][sm][sk] = rb;
            *(int4*)&Bsl[nb][sm][sk] = rbl;
            __syncthreads();
            cur = nb;
        }
    }

    const float is = 1.0f / 2048.0f;
    #pragma unroll
    for (int fi = 0; fi < 2; ++fi) {
        #pragma unroll
        for (int fj = 0; fj < 2; ++fj) {
            int row0 = brow + mr + (fi << 4) + ((lane >> 4) << 2);
            int col  = bcol + nr + (fj << 4) + fr;
            float v[4];
            #pragma unroll
            for (int r = 0; r < 4; ++r)
                v[r] = acc0[fi][fj][r] + acc1[fi][fj][r] * is;
            if (Df) {
                #pragma unroll
                for (int r = 0; r < 4; ++r)
                    Df[(size_t)(row0 + r) * 1024 + col] = v[r];
            }
            if (Dnh) {
                #pragma unroll
                for (int r = 0; r < 4; ++r) {
                    _Float16 h, l;
                    fsplit(v[r], h, l);
                    Dnh[(size_t)(row0 + r) * 1024 + col] = h;
                    Dnl[(size_t)(row0 + r) * 1024 + col] = l;
                }
            }
            if (Dth) {
                half4 hv, lv;
                #pragma unroll
                for (int r = 0; r < 4; ++r) {
                    _Float16 h, l;
                    fsplit(v[r], h, l);
                    hv[r] = h; lv[r] = l;
                }
                *(int2*)&Dth[(size_t)col * 1024 + row0] = __builtin_bit_cast(int2, hv);
                *(int2*)&Dtl[(size_t)col * 1024 + row0] = __builtin_bit_cast(int2, lv);
            }
        }
    }
}

// y[n] = sum_k (Wt_h[n][k] + Wt_l[n][k]/2048) * v[k]; two problems via blockIdx.y
__global__ __launch_bounds__(256) void vecmat_t(
        const _Float16* __restrict__ Wh0, const _Float16* __restrict__ Wl0,
        const float* __restrict__ v0, float* __restrict__ y0,
        const _Float16* __restrict__ Wh1, const _Float16* __restrict__ Wl1,
        const float* __restrict__ v1, float* __restrict__ y1) {
    const _Float16* Wh = blockIdx.y ? Wh1 : Wh0;
    const _Float16* Wl = blockIdx.y ? Wl1 : Wl0;
    const float*    vv = blockIdx.y ? v1 : v0;
    float*          yy = blockIdx.y ? y1 : y0;
    const float is = 1.0f / 2048.0f;
    int n  = blockIdx.x;
    int k0 = threadIdx.x << 2;
    int2 th = *(const int2*)&Wh[(size_t)n * 1024 + k0];
    int2 tl = *(const int2*)&Wl[(size_t)n * 1024 + k0];
    half4 h = __builtin_bit_cast(half4, th);
    half4 l = __builtin_bit_cast(half4, tl);
    float4 b = *(const float4*)&vv[k0];
    float acc = ((float)h[0] + (float)l[0] * is) * b.x
              + ((float)h[1] + (float)l[1] * is) * b.y
              + ((float)h[2] + (float)l[2] * is) * b.z
              + ((float)h[3] + (float)l[3] * is) * b.w;
    #pragma unroll
    for (int o = 1; o < 64; o <<= 1) acc += __shfl_xor(acc, o, 64);
    __shared__ float red[4];
    if ((threadIdx.x & 63) == 0) red[threadIdx.x >> 6] = acc;
    __syncthreads();
    if (threadIdx.x == 0) yy[n] = red[0] + red[1] + red[2] + red[3];
}

// ---------------------------------------------------------------------------
// out[r] = sum_i H[c_i] + g1*beta1p + g2*beta2 + b3
__global__ __launch_bounds__(256) void final_out(const float* __restrict__ H,
                                                 const int* __restrict__ idx,
                                                 const float* __restrict__ dv,
                                                 const float* __restrict__ beta1p,
                                                 const float* __restrict__ beta2,
                                                 const float* __restrict__ b3,
                                                 float* __restrict__ out) {
    const int r = blockIdx.x;
    __shared__ int   sc[KF];
    __shared__ float sd[KF];
    if (threadIdx.x < KF) {
        int c = idx[r * KF + threadIdx.x];
        sc[threadIdx.x] = c;
        sd[threadIdx.x] = dv[c];
    }
    __syncthreads();

    const float s1 = 1.f / 3.f, s2 = 1.f / 9.f, s3 = 1.f / 27.f, s4 = 1.f / 81.f;

    float p = 0.f, q = 0.f, sum2 = 0.f;
    #pragma unroll
    for (int i = 0; i < KF; ++i) {
        float dd = sd[i];
        p += dd;
        sum2 += dd * dd;
        q += dd * dd * dd;
    }
    float u  = (float)KF - sum2;
    float g1 = s2 * u + s1 * q + s3 * p + s4;
    float g2 = s1 * p + s2;

    int j = threadIdx.x << 2;
    float4 bb1 = *(const float4*)&beta1p[j];
    float4 bb2 = *(const float4*)&beta2[j];
    float4 b3v = *(const float4*)&b3[j];
    floatx4 acc;
    acc.x = g1 * bb1.x + g2 * bb2.x + b3v.x;
    acc.y = g1 * bb1.y + g2 * bb2.y + b3v.y;
    acc.z = g1 * bb1.z + g2 * bb2.z + b3v.z;
    acc.w = g1 * bb1.w + g2 * bb2.w + b3v.w;

    #pragma unroll
    for (int i = 0; i < KF; ++i) {
        float4 h = *(const float4*)&H[(size_t)sc[i] * 1024 + j];
        acc.x += h.x;
        acc.y += h.y;
        acc.z += h.z;
        acc.w += h.w;
    }
    __builtin_nontemporal_store(acc, (floatx4*)&out[(size_t)r * 1024 + j]);
}

// ---------------------------------------------------------------------------
extern "C" void kernel_launch(void* const* d_in, const int* in_sizes, int n_in,
                              void* d_out, int out_size, void* d_ws, size_t ws_size,
                              hipStream_t stream) {
    const int*   x   = (const int*)d_in[0];
    const float* emb = (const float*)d_in[1];
    const float* Ws  = (const float*)d_in[2];
    const float* bsv = (const float*)d_in[3];
    float* out = (float*)d_out;

    char* ws = (char*)d_ws;
    const size_t MB = 1 << 20;
    int*   idx    = (int*)(ws);
    int*   cnt    = (int*)(ws + 0x40000);
    float* dv     = (float*)(ws + 0x41000);
    float* wGv    = (float*)(ws + 0x42000);
    float* wCv    = (float*)(ws + 0x43000);
    float* beta1p = (float*)(ws + 0x44000);
    float* beta2  = (float*)(ws + 0x45000);
    float* Mcnt   = (float*)(ws + 1 * MB);
    _Float16* Eh    = (_Float16*)(ws + 5 * MB);
    _Float16* El    = (_Float16*)(ws + 7 * MB);
    _Float16* W1th  = (_Float16*)(ws + 9 * MB);
    _Float16* W1tl  = (_Float16*)(ws + 11 * MB);
    _Float16* W2h   = (_Float16*)(ws + 13 * MB);
    _Float16* W2l   = (_Float16*)(ws + 15 * MB);
    _Float16* W3th  = (_Float16*)(ws + 17 * MB);
    _Float16* W3tl  = (_Float16*)(ws + 19 * MB);
    _Float16* Mph   = (_Float16*)(ws + 21 * MB);
    _Float16* Mpl   = (_Float16*)(ws + 23 * MB);
    _Float16* Ath   = (_Float16*)(ws + 25 * MB);
    _Float16* Atl   = (_Float16*)(ws + 27 * MB);
    _Float16* W23th = (_Float16*)(ws + 29 * MB);
    _Float16* W23tl = (_Float16*)(ws + 31 * MB);
    _Float16* Th    = (_Float16*)(ws + 33 * MB);
    _Float16* Tl    = (_Float16*)(ws + 35 * MB);
    float*    Hm    = (float*)(ws + 37 * MB);

    const float* W1 = Ws;
    const float* W2 = Ws + 1024 * 1024;
    const float* W3 = Ws + 2 * 1024 * 1024;
    const float* b1 = bsv;
    const float* b2 = bsv + 1024;
    const float* b3 = bsv + 2048;

    (void)hipMemsetAsync(cnt, 0, IN_DIM * sizeof(int), stream);
    (void)hipMemsetAsync(Mcnt, 0, (size_t)IN_DIM * IN_DIM * sizeof(float), stream);

    extract_rows<<<N_ROWS / 4, 256, 0, stream>>>(x, idx, cnt);
    compute_w<<<IN_DIM / 256, 256, 0, stream>>>(cnt, dv, wGv, wCv);
    build_M<<<N_ROWS / 4, 256, 0, stream>>>(idx, Mcnt);

    split_nat<<<dim3(1024, 2), 256, 0, stream>>>(emb, W2, Eh, El, W2h, W2l);
    transp_split<<<dim3(16, 16, 2), 256, 0, stream>>>(W1, W3, W1th, W1tl, W3th, W3tl);
    scale_splitM<<<1024, 256, 0, stream>>>(Mcnt, dv, wGv, wCv, Mph, Mpl);

    // S1a: At = (E @ W1)^T   (transposed split out)
    gemm_split<<<dim3(16, 16), 256, 0, stream>>>(Eh, El, W1th, W1tl,
        nullptr, nullptr, nullptr, Ath, Atl);
    // S1b: W23t = (W2 @ W3)^T
    gemm_split<<<dim3(16, 16), 256, 0, stream>>>(W2h, W2l, W3th, W3tl,
        nullptr, nullptr, nullptr, W23th, W23tl);
    // beta1p = b1 @ W23 ; beta2 = b2 @ W3
    vecmat_t<<<dim3(1024, 2), 256, 0, stream>>>(W23th, W23tl, b1, beta1p,
                                                W3th, W3tl, b2, beta2);
    // S2: T = M' @ A   (natural split out)
    gemm_split<<<dim3(16, 16), 256, 0, stream>>>(Mph, Mpl, Ath, Atl,
        nullptr, Th, Tl, nullptr, nullptr);
    // S3: H = T @ W23  (f32 out)
    gemm_split<<<dim3(16, 16), 256, 0, stream>>>(Th, Tl, W23th, W23tl,
        Hm, nullptr, nullptr, nullptr, nullptr);

    final_out<<<N_ROWS, 256, 0, stream>>>(Hm, idx, dv, beta1p, beta2, b3, out);
}

// Round 6
// 168.393 us; speedup vs baseline: 2.5143x; 1.0177x over previous
//
#include <hip/hip_runtime.h>

#define N_ROWS 8192
#define IN_DIM 1024
#define KF     8

typedef _Float16 half8 __attribute__((ext_vector_type(8)));
typedef _Float16 half4 __attribute__((ext_vector_type(4)));
typedef float    floatx4 __attribute__((ext_vector_type(4)));

__device__ __forceinline__ half8 ld_half8(const _Float16* p) {
    int4 t = *(const int4*)p;
    return __builtin_bit_cast(half8, t);
}
__device__ __forceinline__ void fsplit(float v, _Float16& h, _Float16& l) {
    _Float16 x = (_Float16)v;
    h = x;
    l = (_Float16)((v - (float)x) * 2048.0f);
}

// ---------------------------------------------------------------------------
// zero Mcnt (4 MB) + cnt (4 KB) ourselves: rocclr fillBuffer runs at 101 GB/s
// (41 us/replay!); this streams float4 stores at full write BW (~2-3 us).
__global__ void zero_ws(float* __restrict__ Mcnt, int* __restrict__ cnt) {
    size_t i = ((size_t)blockIdx.x * 256 + threadIdx.x) << 2;
    floatx4 z = {0.f, 0.f, 0.f, 0.f};
    *(floatx4*)&Mcnt[i] = z;
    if (blockIdx.x == 0) {
        int4 zi = {0, 0, 0, 0};
        *(int4*)&cnt[threadIdx.x << 2] = zi;
    }
}

// ---------------------------------------------------------------------------
__global__ void extract_rows(const int* __restrict__ x,
                             int* __restrict__ idx,
                             int* __restrict__ cnt) {
    const int r    = blockIdx.x * 4 + (threadIdx.x >> 6);
    const int lane = threadIdx.x & 63;
    const int* row = x + (size_t)r * IN_DIM;

    int vals[16];
    #pragma unroll
    for (int j = 0; j < 4; ++j) {
        int4 v = ((const int4*)row)[lane * 4 + j];
        vals[j * 4 + 0] = v.x;
        vals[j * 4 + 1] = v.y;
        vals[j * 4 + 2] = v.z;
        vals[j * 4 + 3] = v.w;
    }
    int c = 0;
    #pragma unroll
    for (int j = 0; j < 16; ++j) c += (vals[j] != 0);

    int s = c;
    #pragma unroll
    for (int o = 1; o < 64; o <<= 1) {
        int t = __shfl_up(s, o, 64);
        if (lane >= o) s += t;
    }
    int pos = s - c;

    #pragma unroll
    for (int j = 0; j < 16; ++j) {
        if (vals[j] != 0) {
            int col = lane * 16 + j;
            if (pos < KF) idx[r * KF + pos] = col;
            pos++;
            atomicAdd(&cnt[col], 1);
        }
    }
}

__global__ void compute_w(const int* __restrict__ cnt, float* __restrict__ dv,
                          float* __restrict__ wGv, float* __restrict__ wCv) {
    const float s1 = 1.f / 3.f, s3 = 1.f / 27.f, s5 = 1.f / 243.f;
    int c = blockIdx.x * 256 + threadIdx.x;
    float d  = rsqrtf((float)cnt[c] + 1.0f);
    float d2 = d * d;
    dv[c]  = d;
    wGv[c] = s3 * d2;
    wCv[c] = d * (s1 * d2 * d2 + s3 * d2 + s5);
}

// co-occurrence counts (integer-exact f32 atomics -> deterministic)
__global__ void build_M(const int* __restrict__ idx, float* __restrict__ M) {
    const int r = blockIdx.x * 4 + (threadIdx.x >> 6);
    const int t = threadIdx.x & 63;
    const int i = t >> 3, j = t & 7;
    int ci = idx[r * KF + i];
    int cj = idx[r * KF + j];
    atomicAdd(&M[ci * IN_DIM + cj], 1.0f);
}

// M'[i][j] = wG[i]*Mcnt[i][j]*dv[j] + (i==j)*wC[i], split to f16 hi/lo
__global__ void scale_splitM(const float* __restrict__ Mc, const float* __restrict__ dv,
                             const float* __restrict__ wGv, const float* __restrict__ wCv,
                             _Float16* __restrict__ Mh, _Float16* __restrict__ Ml) {
    size_t i = ((size_t)blockIdx.x * 256 + threadIdx.x) << 2;
    int row = (int)(i >> 10);
    int cb  = (int)(i & 1023);
    float wg = wGv[row];
    float4 m  = *(const float4*)&Mc[i];
    float4 dd = *(const float4*)&dv[cb];
    float v[4] = {m.x * dd.x * wg, m.y * dd.y * wg, m.z * dd.z * wg, m.w * dd.w * wg};
    #pragma unroll
    for (int j = 0; j < 4; ++j)
        if (cb + j == row) v[j] += wCv[row];
    half4 h, l;
    #pragma unroll
    for (int j = 0; j < 4; ++j) { _Float16 hh, ll; fsplit(v[j], hh, ll); h[j] = hh; l[j] = ll; }
    *(int2*)&Mh[i] = __builtin_bit_cast(int2, h);
    *(int2*)&Ml[i] = __builtin_bit_cast(int2, l);
}

// natural split f32 -> f16 hi/lo (E and W2 via blockIdx.y)
__global__ void split_nat(const float* __restrict__ S0, const float* __restrict__ S1,
                          _Float16* __restrict__ H0, _Float16* __restrict__ L0,
                          _Float16* __restrict__ H1, _Float16* __restrict__ L1) {
    const float* S = blockIdx.y ? S1 : S0;
    _Float16* Hp = blockIdx.y ? H1 : H0;
    _Float16* Lp = blockIdx.y ? L1 : L0;
    size_t i = ((size_t)blockIdx.x * 256 + threadIdx.x) << 2;
    float4 v = *(const float4*)&S[i];
    float vv[4] = {v.x, v.y, v.z, v.w};
    half4 h, l;
    #pragma unroll
    for (int j = 0; j < 4; ++j) { _Float16 hh, ll; fsplit(vv[j], hh, ll); h[j] = hh; l[j] = ll; }
    *(int2*)&Hp[i] = __builtin_bit_cast(int2, h);
    *(int2*)&Lp[i] = __builtin_bit_cast(int2, l);
}

// transposed split: O[n][k] = split(S[k][n])  (W1 and W3 via blockIdx.z)
__global__ __launch_bounds__(256) void transp_split(
        const float* __restrict__ S0, const float* __restrict__ S1,
        _Float16* __restrict__ H0, _Float16* __restrict__ L0,
        _Float16* __restrict__ H1, _Float16* __restrict__ L1) {
    const float* S = blockIdx.z ? S1 : S0;
    _Float16* Hp = blockIdx.z ? H1 : H0;
    _Float16* Lp = blockIdx.z ? L1 : L0;
    __shared__ float sh[64][65];
    const int r0 = blockIdx.y << 6, c0 = blockIdx.x << 6;
    #pragma unroll
    for (int it = 0; it < 4; ++it) {
        int r = (threadIdx.x >> 4) + (it << 4);
        int c = (threadIdx.x & 15) << 2;
        float4 v = *(const float4*)&S[(size_t)(r0 + r) * 1024 + c0 + c];
        sh[r][c] = v.x; sh[r][c + 1] = v.y; sh[r][c + 2] = v.z; sh[r][c + 3] = v.w;
    }
    __syncthreads();
    int nl = threadIdx.x >> 2;
    #pragma unroll
    for (int cc = 0; cc < 2; ++cc) {
        int kq = ((threadIdx.x & 3) << 4) + (cc << 3);
        half8 h, l;
        #pragma unroll
        for (int j = 0; j < 8; ++j) {
            _Float16 hh, ll;
            fsplit(sh[kq + j][nl], hh, ll);
            h[j] = hh; l[j] = ll;
        }
        *(int4*)&Hp[(size_t)(c0 + nl) * 1024 + r0 + kq] = __builtin_bit_cast(int4, h);
        *(int4*)&Lp[(size_t)(c0 + nl) * 1024 + r0 + kq] = __builtin_bit_cast(int4, l);
    }
}

// ---------------------------------------------------------------------------
// split-f16 MFMA GEMM: D[1024x1024] = A @ B, A given split natural (h/l),
// B given split TRANSPOSED ([n][k]).  64x64 tile, 4 waves, 2x2 frags of
// 16x16x32 per wave, 3 MFMA per frag (hh, h*l, l*h), dbuf LDS.
// Epilogue: optional f32 / natural-split / transposed-split outputs.
__global__ __launch_bounds__(256) void gemm_split(
    const _Float16* __restrict__ Agh, const _Float16* __restrict__ Agl,
    const _Float16* __restrict__ Bgh, const _Float16* __restrict__ Bgl,
    float* __restrict__ Df,
    _Float16* __restrict__ Dnh, _Float16* __restrict__ Dnl,
    _Float16* __restrict__ Dth, _Float16* __restrict__ Dtl)
{
    __shared__ _Float16 Ash[2][64][40];
    __shared__ _Float16 Asl[2][64][40];
    __shared__ _Float16 Bsh[2][64][40];
    __shared__ _Float16 Bsl[2][64][40];

    const int tid  = threadIdx.x;
    const int lane = tid & 63;
    const int w    = tid >> 6;
    const int mr   = (w >> 1) << 5;
    const int nr   = (w & 1) << 5;
    const int brow = blockIdx.y << 6;
    const int bcol = blockIdx.x << 6;

    const int sm = tid >> 2;           // staged row 0..63
    const int sk = (tid & 3) << 3;     // staged k offset 0,8,16,24

    const _Float16* pAh = Agh + (size_t)(brow + sm) * 1024 + sk;
    const _Float16* pAl = Agl + (size_t)(brow + sm) * 1024 + sk;
    const _Float16* pBh = Bgh + (size_t)(bcol + sm) * 1024 + sk;
    const _Float16* pBl = Bgl + (size_t)(bcol + sm) * 1024 + sk;

    const int fr = lane & 15;
    const int fk = (lane >> 4) << 3;   // per-lane k offset within 32

    floatx4 acc0[2][2] = {};
    floatx4 acc1[2][2] = {};

    int4 ra, rl, rb, rbl;
    ra  = *(const int4*)pAh;
    rl  = *(const int4*)pAl;
    rb  = *(const int4*)pBh;
    rbl = *(const int4*)pBl;
    *(int4*)&Ash[0][sm][sk] = ra;
    *(int4*)&Asl[0][sm][sk] = rl;
    *(int4*)&Bsh[0][sm][sk] = rb;
    *(int4*)&Bsl[0][sm][sk] = rbl;
    __syncthreads();

    int cur = 0;
    for (int kt = 1; kt <= 32; ++kt) {
        if (kt < 32) {
            size_t o = (size_t)kt * 32;
            ra  = *(const int4*)(pAh + o);
            rl  = *(const int4*)(pAl + o);
            rb  = *(const int4*)(pBh + o);
            rbl = *(const int4*)(pBl + o);
        }
        half8 afh[2], afl[2], bfh[2], bfl[2];
        #pragma unroll
        for (int f = 0; f < 2; ++f) {
            afh[f] = ld_half8(&Ash[cur][mr + (f << 4) + fr][fk]);
            afl[f] = ld_half8(&Asl[cur][mr + (f << 4) + fr][fk]);
            bfh[f] = ld_half8(&Bsh[cur][nr + (f << 4) + fr][fk]);
            bfl[f] = ld_half8(&Bsl[cur][nr + (f << 4) + fr][fk]);
        }
        #pragma unroll
        for (int fi = 0; fi < 2; ++fi)
            #pragma unroll
            for (int fj = 0; fj < 2; ++fj)
                acc0[fi][fj] = __builtin_amdgcn_mfma_f32_16x16x32_f16(afh[fi], bfh[fj], acc0[fi][fj], 0, 0, 0);
        #pragma unroll
        for (int fi = 0; fi < 2; ++fi)
            #pragma unroll
            for (int fj = 0; fj < 2; ++fj)
                acc1[fi][fj] = __builtin_amdgcn_mfma_f32_16x16x32_f16(afh[fi], bfl[fj], acc1[fi][fj], 0, 0, 0);
        #pragma unroll
        for (int fi = 0; fi < 2; ++fi)
            #pragma unroll
            for (int fj = 0; fj < 2; ++fj)
                acc1[fi][fj] = __builtin_amdgcn_mfma_f32_16x16x32_f16(afl[fi], bfh[fj], acc1[fi][fj], 0, 0, 0);

        if (kt < 32) {
            int nb = cur ^ 1;
            *(int4*)&Ash[nb][sm][sk] = ra;
            *(int4*)&Asl[nb][sm][sk] = rl;
            *(int4*)&Bsh[nb][sm][sk] = rb;
            *(int4*)&Bsl[nb][sm][sk] = rbl;
            __syncthreads();
            cur = nb;
        }
    }

    const float is = 1.0f / 2048.0f;
    #pragma unroll
    for (int fi = 0; fi < 2; ++fi) {
        #pragma unroll
        for (int fj = 0; fj < 2; ++fj) {
            int row0 = brow + mr + (fi << 4) + ((lane >> 4) << 2);
            int col  = bcol + nr + (fj << 4) + fr;
            float v[4];
            #pragma unroll
            for (int r = 0; r < 4; ++r)
                v[r] = acc0[fi][fj][r] + acc1[fi][fj][r] * is;
            if (Df) {
                #pragma unroll
                for (int r = 0; r < 4; ++r)
                    Df[(size_t)(row0 + r) * 1024 + col] = v[r];
            }
            if (Dnh) {
                #pragma unroll
                for (int r = 0; r < 4; ++r) {
                    _Float16 h, l;
                    fsplit(v[r], h, l);
                    Dnh[(size_t)(row0 + r) * 1024 + col] = h;
                    Dnl[(size_t)(row0 + r) * 1024 + col] = l;
                }
            }
            if (Dth) {
                half4 hv, lv;
                #pragma unroll
                for (int r = 0; r < 4; ++r) {
                    _Float16 h, l;
                    fsplit(v[r], h, l);
                    hv[r] = h; lv[r] = l;
                }
                *(int2*)&Dth[(size_t)col * 1024 + row0] = __builtin_bit_cast(int2, hv);
                *(int2*)&Dtl[(size_t)col * 1024 + row0] = __builtin_bit_cast(int2, lv);
            }
        }
    }
}

// y[n] = sum_k (Wt_h[n][k] + Wt_l[n][k]/2048) * v[k]; two problems via blockIdx.y
__global__ __launch_bounds__(256) void vecmat_t(
        const _Float16* __restrict__ Wh0, const _Float16* __restrict__ Wl0,
        const float* __restrict__ v0, float* __restrict__ y0,
        const _Float16* __restrict__ Wh1, const _Float16* __restrict__ Wl1,
        const float* __restrict__ v1, float* __restrict__ y1) {
    const _Float16* Wh = blockIdx.y ? Wh1 : Wh0;
    const _Float16* Wl = blockIdx.y ? Wl1 : Wl0;
    const float*    vv = blockIdx.y ? v1 : v0;
    float*          yy = blockIdx.y ? y1 : y0;
    const float is = 1.0f / 2048.0f;
    int n  = blockIdx.x;
    int k0 = threadIdx.x << 2;
    int2 th = *(const int2*)&Wh[(size_t)n * 1024 + k0];
    int2 tl = *(const int2*)&Wl[(size_t)n * 1024 + k0];
    half4 h = __builtin_bit_cast(half4, th);
    half4 l = __builtin_bit_cast(half4, tl);
    float4 b = *(const float4*)&vv[k0];
    float acc = ((float)h[0] + (float)l[0] * is) * b.x
              + ((float)h[1] + (float)l[1] * is) * b.y
              + ((float)h[2] + (float)l[2] * is) * b.z
              + ((float)h[3] + (float)l[3] * is) * b.w;
    #pragma unroll
    for (int o = 1; o < 64; o <<= 1) acc += __shfl_xor(acc, o, 64);
    __shared__ float red[4];
    if ((threadIdx.x & 63) == 0) red[threadIdx.x >> 6] = acc;
    __syncthreads();
    if (threadIdx.x == 0) yy[n] = red[0] + red[1] + red[2] + red[3];
}

// ---------------------------------------------------------------------------
// out[r] = sum_i H[c_i] + g1*beta1p + g2*beta2 + b3
__global__ __launch_bounds__(256) void final_out(const float* __restrict__ H,
                                                 const int* __restrict__ idx,
                                                 const float* __restrict__ dv,
                                                 const float* __restrict__ beta1p,
                                                 const float* __restrict__ beta2,
                                                 const float* __restrict__ b3,
                                                 float* __restrict__ out) {
    const int r = blockIdx.x;
    __shared__ int   sc[KF];
    __shared__ float sd[KF];
    if (threadIdx.x < KF) {
        int c = idx[r * KF + threadIdx.x];
        sc[threadIdx.x] = c;
        sd[threadIdx.x] = dv[c];
    }
    __syncthreads();

    const float s1 = 1.f / 3.f, s2 = 1.f / 9.f, s3 = 1.f / 27.f, s4 = 1.f / 81.f;

    float p = 0.f, q = 0.f, sum2 = 0.f;
    #pragma unroll
    for (int i = 0; i < KF; ++i) {
        float dd = sd[i];
        p += dd;
        sum2 += dd * dd;
        q += dd * dd * dd;
    }
    float u  = (float)KF - sum2;
    float g1 = s2 * u + s1 * q + s3 * p + s4;
    float g2 = s1 * p + s2;

    int j = threadIdx.x << 2;
    float4 bb1 = *(const float4*)&beta1p[j];
    float4 bb2 = *(const float4*)&beta2[j];
    float4 b3v = *(const float4*)&b3[j];
    floatx4 acc;
    acc.x = g1 * bb1.x + g2 * bb2.x + b3v.x;
    acc.y = g1 * bb1.y + g2 * bb2.y + b3v.y;
    acc.z = g1 * bb1.z + g2 * bb2.z + b3v.z;
    acc.w = g1 * bb1.w + g2 * bb2.w + b3v.w;

    #pragma unroll
    for (int i = 0; i < KF; ++i) {
        float4 h = *(const float4*)&H[(size_t)sc[i] * 1024 + j];
        acc.x += h.x;
        acc.y += h.y;
        acc.z += h.z;
        acc.w += h.w;
    }
    __builtin_nontemporal_store(acc, (floatx4*)&out[(size_t)r * 1024 + j]);
}

// ---------------------------------------------------------------------------
extern "C" void kernel_launch(void* const* d_in, const int* in_sizes, int n_in,
                              void* d_out, int out_size, void* d_ws, size_t ws_size,
                              hipStream_t stream) {
    const int*   x   = (const int*)d_in[0];
    const float* emb = (const float*)d_in[1];
    const float* Ws  = (const float*)d_in[2];
    const float* bsv = (const float*)d_in[3];
    float* out = (float*)d_out;

    char* ws = (char*)d_ws;
    const size_t MB = 1 << 20;
    int*   idx    = (int*)(ws);
    int*   cnt    = (int*)(ws + 0x40000);
    float* dv     = (float*)(ws + 0x41000);
    float* wGv    = (float*)(ws + 0x42000);
    float* wCv    = (float*)(ws + 0x43000);
    float* beta1p = (float*)(ws + 0x44000);
    float* beta2  = (float*)(ws + 0x45000);
    float* Mcnt   = (float*)(ws + 1 * MB);
    _Float16* Eh    = (_Float16*)(ws + 5 * MB);
    _Float16* El    = (_Float16*)(ws + 7 * MB);
    _Float16* W1th  = (_Float16*)(ws + 9 * MB);
    _Float16* W1tl  = (_Float16*)(ws + 11 * MB);
    _Float16* W2h   = (_Float16*)(ws + 13 * MB);
    _Float16* W2l   = (_Float16*)(ws + 15 * MB);
    _Float16* W3th  = (_Float16*)(ws + 17 * MB);
    _Float16* W3tl  = (_Float16*)(ws + 19 * MB);
    _Float16* Mph   = (_Float16*)(ws + 21 * MB);
    _Float16* Mpl   = (_Float16*)(ws + 23 * MB);
    _Float16* Ath   = (_Float16*)(ws + 25 * MB);
    _Float16* Atl   = (_Float16*)(ws + 27 * MB);
    _Float16* W23th = (_Float16*)(ws + 29 * MB);
    _Float16* W23tl = (_Float16*)(ws + 31 * MB);
    _Float16* Th    = (_Float16*)(ws + 33 * MB);
    _Float16* Tl    = (_Float16*)(ws + 35 * MB);
    float*    Hm    = (float*)(ws + 37 * MB);

    const float* W1 = Ws;
    const float* W2 = Ws + 1024 * 1024;
    const float* W3 = Ws + 2 * 1024 * 1024;
    const float* b1 = bsv;
    const float* b2 = bsv + 1024;
    const float* b3 = bsv + 2048;

    zero_ws<<<1024, 256, 0, stream>>>(Mcnt, cnt);

    extract_rows<<<N_ROWS / 4, 256, 0, stream>>>(x, idx, cnt);
    compute_w<<<IN_DIM / 256, 256, 0, stream>>>(cnt, dv, wGv, wCv);
    build_M<<<N_ROWS / 4, 256, 0, stream>>>(idx, Mcnt);

    split_nat<<<dim3(1024, 2), 256, 0, stream>>>(emb, W2, Eh, El, W2h, W2l);
    transp_split<<<dim3(16, 16, 2), 256, 0, stream>>>(W1, W3, W1th, W1tl, W3th, W3tl);
    scale_splitM<<<1024, 256, 0, stream>>>(Mcnt, dv, wGv, wCv, Mph, Mpl);

    // S1a: At = (E @ W1)^T   (transposed split out)
    gemm_split<<<dim3(16, 16), 256, 0, stream>>>(Eh, El, W1th, W1tl,
        nullptr, nullptr, nullptr, Ath, Atl);
    // S1b: W23t = (W2 @ W3)^T
    gemm_split<<<dim3(16, 16), 256, 0, stream>>>(W2h, W2l, W3th, W3tl,
        nullptr, nullptr, nullptr, W23th, W23tl);
    // beta1p = b1 @ W23 ; beta2 = b2 @ W3
    vecmat_t<<<dim3(1024, 2), 256, 0, stream>>>(W23th, W23tl, b1, beta1p,
                                                W3th, W3tl, b2, beta2);
    // S2: T = M' @ A   (natural split out)
    gemm_split<<<dim3(16, 16), 256, 0, stream>>>(Mph, Mpl, Ath, Atl,
        nullptr, Th, Tl, nullptr, nullptr);
    // S3: H = T @ W23  (f32 out)
    gemm_split<<<dim3(16, 16), 256, 0, stream>>>(Th, Tl, W23th, W23tl,
        Hm, nullptr, nullptr, nullptr, nullptr);

    final_out<<<N_ROWS, 256, 0, stream>>>(Hm, idx, dv, beta1p, beta2, b3, out);
}

// Round 7
// 155.744 us; speedup vs baseline: 2.7185x; 1.0812x over previous
//
#include <hip/hip_runtime.h>

#define N_ROWS 8192
#define IN_DIM 1024
#define KF     8

typedef _Float16 half8 __attribute__((ext_vector_type(8)));
typedef _Float16 half4 __attribute__((ext_vector_type(4)));
typedef float    floatx4 __attribute__((ext_vector_type(4)));
typedef float    floatx16 __attribute__((ext_vector_type(16)));

__device__ __forceinline__ half8 ld_half8(const _Float16* p) {
    int4 t = *(const int4*)p;
    return __builtin_bit_cast(half8, t);
}
__device__ __forceinline__ void fsplit(float v, _Float16& h, _Float16& l) {
    _Float16 x = (_Float16)v;
    h = x;
    l = (_Float16)((v - (float)x) * 2048.0f);
}
// async global->LDS, 16B per lane; lds dst is wave-uniform base (+lane*16 by HW)
__device__ __forceinline__ void gload16(const _Float16* g, _Float16* l) {
    __builtin_amdgcn_global_load_lds(
        (const __attribute__((address_space(1))) void*)g,
        (__attribute__((address_space(3))) void*)l,
        16, 0, 0);
}

// ---------------------------------------------------------------------------
__global__ void zero_ws(float* __restrict__ Mcnt, int* __restrict__ cnt) {
    size_t i = ((size_t)blockIdx.x * 256 + threadIdx.x) << 2;
    floatx4 z = {0.f, 0.f, 0.f, 0.f};
    *(floatx4*)&Mcnt[i] = z;
    if (blockIdx.x == 0) {
        int4 zi = {0, 0, 0, 0};
        *(int4*)&cnt[threadIdx.x << 2] = zi;
    }
}

// ---------------------------------------------------------------------------
__global__ void extract_rows(const int* __restrict__ x,
                             int* __restrict__ idx,
                             int* __restrict__ cnt) {
    const int r    = blockIdx.x * 4 + (threadIdx.x >> 6);
    const int lane = threadIdx.x & 63;
    const int* row = x + (size_t)r * IN_DIM;

    int vals[16];
    #pragma unroll
    for (int j = 0; j < 4; ++j) {
        int4 v = ((const int4*)row)[lane * 4 + j];
        vals[j * 4 + 0] = v.x;
        vals[j * 4 + 1] = v.y;
        vals[j * 4 + 2] = v.z;
        vals[j * 4 + 3] = v.w;
    }
    int c = 0;
    #pragma unroll
    for (int j = 0; j < 16; ++j) c += (vals[j] != 0);

    int s = c;
    #pragma unroll
    for (int o = 1; o < 64; o <<= 1) {
        int t = __shfl_up(s, o, 64);
        if (lane >= o) s += t;
    }
    int pos = s - c;

    #pragma unroll
    for (int j = 0; j < 16; ++j) {
        if (vals[j] != 0) {
            int col = lane * 16 + j;
            if (pos < KF) idx[r * KF + pos] = col;
            pos++;
            atomicAdd(&cnt[col], 1);
        }
    }
}

__global__ void compute_w(const int* __restrict__ cnt, float* __restrict__ dv,
                          float* __restrict__ wGv, float* __restrict__ wCv) {
    const float s1 = 1.f / 3.f, s3 = 1.f / 27.f, s5 = 1.f / 243.f;
    int c = blockIdx.x * 256 + threadIdx.x;
    float d  = rsqrtf((float)cnt[c] + 1.0f);
    float d2 = d * d;
    dv[c]  = d;
    wGv[c] = s3 * d2;
    wCv[c] = d * (s1 * d2 * d2 + s3 * d2 + s5);
}

// co-occurrence counts (integer-exact f32 atomics -> deterministic)
__global__ void build_M(const int* __restrict__ idx, float* __restrict__ M) {
    const int r = blockIdx.x * 4 + (threadIdx.x >> 6);
    const int t = threadIdx.x & 63;
    const int i = t >> 3, j = t & 7;
    int ci = idx[r * KF + i];
    int cj = idx[r * KF + j];
    atomicAdd(&M[ci * IN_DIM + cj], 1.0f);
}

// M'[i][j] = wG[i]*Mcnt[i][j]*dv[j] + (i==j)*wC[i], split to f16 hi/lo
__global__ void scale_splitM(const float* __restrict__ Mc, const float* __restrict__ dv,
                             const float* __restrict__ wGv, const float* __restrict__ wCv,
                             _Float16* __restrict__ Mh, _Float16* __restrict__ Ml) {
    size_t i = ((size_t)blockIdx.x * 256 + threadIdx.x) << 2;
    int row = (int)(i >> 10);
    int cb  = (int)(i & 1023);
    float wg = wGv[row];
    float4 m  = *(const float4*)&Mc[i];
    float4 dd = *(const float4*)&dv[cb];
    float v[4] = {m.x * dd.x * wg, m.y * dd.y * wg, m.z * dd.z * wg, m.w * dd.w * wg};
    #pragma unroll
    for (int j = 0; j < 4; ++j)
        if (cb + j == row) v[j] += wCv[row];
    half4 h, l;
    #pragma unroll
    for (int j = 0; j < 4; ++j) { _Float16 hh, ll; fsplit(v[j], hh, ll); h[j] = hh; l[j] = ll; }
    *(int2*)&Mh[i] = __builtin_bit_cast(int2, h);
    *(int2*)&Ml[i] = __builtin_bit_cast(int2, l);
}

// natural split f32 -> f16 hi/lo (E and W2 via blockIdx.y)
__global__ void split_nat(const float* __restrict__ S0, const float* __restrict__ S1,
                          _Float16* __restrict__ H0, _Float16* __restrict__ L0,
                          _Float16* __restrict__ H1, _Float16* __restrict__ L1) {
    const float* S = blockIdx.y ? S1 : S0;
    _Float16* Hp = blockIdx.y ? H1 : H0;
    _Float16* Lp = blockIdx.y ? L1 : L0;
    size_t i = ((size_t)blockIdx.x * 256 + threadIdx.x) << 2;
    float4 v = *(const float4*)&S[i];
    float vv[4] = {v.x, v.y, v.z, v.w};
    half4 h, l;
    #pragma unroll
    for (int j = 0; j < 4; ++j) { _Float16 hh, ll; fsplit(vv[j], hh, ll); h[j] = hh; l[j] = ll; }
    *(int2*)&Hp[i] = __builtin_bit_cast(int2, h);
    *(int2*)&Lp[i] = __builtin_bit_cast(int2, l);
}

// transposed split: O[n][k] = split(S[k][n])  (W1 and W3 via blockIdx.z)
__global__ __launch_bounds__(256) void transp_split(
        const float* __restrict__ S0, const float* __restrict__ S1,
        _Float16* __restrict__ H0, _Float16* __restrict__ L0,
        _Float16* __restrict__ H1, _Float16* __restrict__ L1) {
    const float* S = blockIdx.z ? S1 : S0;
    _Float16* Hp = blockIdx.z ? H1 : H0;
    _Float16* Lp = blockIdx.z ? L1 : L0;
    __shared__ float sh[64][65];
    const int r0 = blockIdx.y << 6, c0 = blockIdx.x << 6;
    #pragma unroll
    for (int it = 0; it < 4; ++it) {
        int r = (threadIdx.x >> 4) + (it << 4);
        int c = (threadIdx.x & 15) << 2;
        float4 v = *(const float4*)&S[(size_t)(r0 + r) * 1024 + c0 + c];
        sh[r][c] = v.x; sh[r][c + 1] = v.y; sh[r][c + 2] = v.z; sh[r][c + 3] = v.w;
    }
    __syncthreads();
    int nl = threadIdx.x >> 2;
    #pragma unroll
    for (int cc = 0; cc < 2; ++cc) {
        int kq = ((threadIdx.x & 3) << 4) + (cc << 3);
        half8 h, l;
        #pragma unroll
        for (int j = 0; j < 8; ++j) {
            _Float16 hh, ll;
            fsplit(sh[kq + j][nl], hh, ll);
            h[j] = hh; l[j] = ll;
        }
        *(int4*)&Hp[(size_t)(c0 + nl) * 1024 + r0 + kq] = __builtin_bit_cast(int4, h);
        *(int4*)&Lp[(size_t)(c0 + nl) * 1024 + r0 + kq] = __builtin_bit_cast(int4, l);
    }
}

// ---------------------------------------------------------------------------
// split-f16 MFMA GEMM v2: 64x64 tile, 4 waves, one 32x32x16 frag-chain per
// wave (3 MFMA per K=16: hh, h*l, l*h), BK=64, double-buffered LDS filled by
// global_load_lds width=16 with pre-swizzled source (XOR chunk^row&7) and
// swizzled ds_read_b128 -> conflict-free. Two problem descriptors, z-select.
struct GemmDesc {
    const _Float16 *Ah, *Al;   // A natural [m][k]
    const _Float16 *Bh, *Bl;   // B transposed [n][k]
    float* Df;                 // optional f32 out
    _Float16 *Dnh, *Dnl;       // optional natural split out
    _Float16 *Dth, *Dtl;       // optional transposed split out
};

__global__ __launch_bounds__(256) void gemm_split(GemmDesc d0, GemmDesc d1)
{
    GemmDesc d = blockIdx.z ? d1 : d0;
    __shared__ _Float16 lds[2][4][64][64];   // [buf][Ah,Al,Bh,Bl][row][k] 64 KB

    const int tid  = threadIdx.x;
    const int lane = tid & 63;
    const int w    = tid >> 6;
    const int wm   = w >> 1, wn = w & 1;
    const int brow = blockIdx.y << 6;
    const int bcol = blockIdx.x << 6;

    // --- staging: wave w stages array w; 8 calls x 64 lanes x 16B = 8 KB
    const _Float16* gsrc = (w == 0) ? d.Ah : (w == 1) ? d.Al : (w == 2) ? d.Bh : d.Bl;
    const int rowbase = (w < 2) ? brow : bcol;
    // lane covers row (c*8 + lane>>3), chunk lane&7; source chunk pre-swizzled
    const int swz = (((lane & 7) ^ ((lane >> 3) & 7)) << 3);
    const _Float16* gbase = gsrc + (size_t)(rowbase + (lane >> 3)) * 1024 + swz;

#define STAGE(kt_, buf_) do {                                              \
        _Float16* lb = &lds[buf_][w][0][0];                                \
        const _Float16* gb = gbase + ((kt_) << 6);                         \
        _Pragma("unroll")                                                  \
        for (int c = 0; c < 8; ++c)                                        \
            gload16(gb + ((size_t)(c << 3) << 10), lb + (c << 9));         \
    } while (0)

    // --- compute geometry
    const int l31  = lane & 31;
    const int kh   = lane >> 5;          // k-half within K=16
    const int arow = (wm << 5) + l31;    // A slab row 0..63
    const int brw  = (wn << 5) + l31;    // B slab row 0..63
    const int r7   = l31 & 7;            // row&7 (same for A and B)

    floatx16 acc0 = {};
    floatx16 acc1 = {};

    STAGE(0, 0);
    __syncthreads();

    int cur = 0;
    for (int kt = 0; kt < 16; ++kt) {
        if (kt < 15) STAGE(kt + 1, cur ^ 1);
        const _Float16* pa_h = &lds[cur][0][arow][0];
        const _Float16* pa_l = &lds[cur][1][arow][0];
        const _Float16* pb_h = &lds[cur][2][brw][0];
        const _Float16* pb_l = &lds[cur][3][brw][0];
        #pragma unroll
        for (int kc = 0; kc < 4; ++kc) {
            int ca = ((((kc << 1) | kh) ^ r7) << 3);
            half8 ah = ld_half8(pa_h + ca);
            half8 al = ld_half8(pa_l + ca);
            half8 bh = ld_half8(pb_h + ca);
            half8 bl = ld_half8(pb_l + ca);
            acc0 = __builtin_amdgcn_mfma_f32_32x32x16_f16(ah, bh, acc0, 0, 0, 0);
            acc1 = __builtin_amdgcn_mfma_f32_32x32x16_f16(ah, bl, acc1, 0, 0, 0);
            acc1 = __builtin_amdgcn_mfma_f32_32x32x16_f16(al, bh, acc1, 0, 0, 0);
        }
        if (kt < 15) {
            __syncthreads();
            cur ^= 1;
        }
    }
#undef STAGE

    // --- epilogue: C/D layout col=lane&31, row=(r&3)+8*(r>>2)+4*(lane>>5)
    const float is = 1.0f / 2048.0f;
    const int grow = brow + (wm << 5) + (kh << 2);
    const int gcol = bcol + (wn << 5) + l31;

    if (d.Df) {
        #pragma unroll
        for (int r = 0; r < 16; ++r) {
            int row = grow + (r & 3) + ((r >> 2) << 3);
            d.Df[(size_t)row * 1024 + gcol] = acc0[r] + acc1[r] * is;
        }
    }
    if (d.Dnh) {
        #pragma unroll
        for (int r = 0; r < 16; ++r) {
            int row = grow + (r & 3) + ((r >> 2) << 3);
            _Float16 h, l;
            fsplit(acc0[r] + acc1[r] * is, h, l);
            d.Dnh[(size_t)row * 1024 + gcol] = h;
            d.Dnl[(size_t)row * 1024 + gcol] = l;
        }
    }
    if (d.Dth) {
        #pragma unroll
        for (int g = 0; g < 4; ++g) {
            half4 hv, lv;
            #pragma unroll
            for (int j = 0; j < 4; ++j) {
                int r = (g << 2) + j;
                _Float16 h, l;
                fsplit(acc0[r] + acc1[r] * is, h, l);
                hv[j] = h; lv[j] = l;
            }
            int row = grow + (g << 3);
            *(int2*)&d.Dth[(size_t)gcol * 1024 + row] = __builtin_bit_cast(int2, hv);
            *(int2*)&d.Dtl[(size_t)gcol * 1024 + row] = __builtin_bit_cast(int2, lv);
        }
    }
}

// y[n] = sum_k (Wt_h[n][k] + Wt_l[n][k]/2048) * v[k]; two problems via blockIdx.y
__global__ __launch_bounds__(256) void vecmat_t(
        const _Float16* __restrict__ Wh0, const _Float16* __restrict__ Wl0,
        const float* __restrict__ v0, float* __restrict__ y0,
        const _Float16* __restrict__ Wh1, const _Float16* __restrict__ Wl1,
        const float* __restrict__ v1, float* __restrict__ y1) {
    const _Float16* Wh = blockIdx.y ? Wh1 : Wh0;
    const _Float16* Wl = blockIdx.y ? Wl1 : Wl0;
    const float*    vv = blockIdx.y ? v1 : v0;
    float*          yy = blockIdx.y ? y1 : y0;
    const float is = 1.0f / 2048.0f;
    int n  = blockIdx.x;
    int k0 = threadIdx.x << 2;
    int2 th = *(const int2*)&Wh[(size_t)n * 1024 + k0];
    int2 tl = *(const int2*)&Wl[(size_t)n * 1024 + k0];
    half4 h = __builtin_bit_cast(half4, th);
    half4 l = __builtin_bit_cast(half4, tl);
    float4 b = *(const float4*)&vv[k0];
    float acc = ((float)h[0] + (float)l[0] * is) * b.x
              + ((float)h[1] + (float)l[1] * is) * b.y
              + ((float)h[2] + (float)l[2] * is) * b.z
              + ((float)h[3] + (float)l[3] * is) * b.w;
    #pragma unroll
    for (int o = 1; o < 64; o <<= 1) acc += __shfl_xor(acc, o, 64);
    __shared__ float red[4];
    if ((threadIdx.x & 63) == 0) red[threadIdx.x >> 6] = acc;
    __syncthreads();
    if (threadIdx.x == 0) yy[n] = red[0] + red[1] + red[2] + red[3];
}

// ---------------------------------------------------------------------------
// out[r] = sum_i H[c_i] + g1*beta1p + g2*beta2 + b3
__global__ __launch_bounds__(256) void final_out(const float* __restrict__ H,
                                                 const int* __restrict__ idx,
                                                 const float* __restrict__ dv,
                                                 const float* __restrict__ beta1p,
                                                 const float* __restrict__ beta2,
                                                 const float* __restrict__ b3,
                                                 float* __restrict__ out) {
    const int r = blockIdx.x;
    __shared__ int   sc[KF];
    __shared__ float sd[KF];
    if (threadIdx.x < KF) {
        int c = idx[r * KF + threadIdx.x];
        sc[threadIdx.x] = c;
        sd[threadIdx.x] = dv[c];
    }
    __syncthreads();

    const float s1 = 1.f / 3.f, s2 = 1.f / 9.f, s3 = 1.f / 27.f, s4 = 1.f / 81.f;

    float p = 0.f, q = 0.f, sum2 = 0.f;
    #pragma unroll
    for (int i = 0; i < KF; ++i) {
        float dd = sd[i];
        p += dd;
        sum2 += dd * dd;
        q += dd * dd * dd;
    }
    float u  = (float)KF - sum2;
    float g1 = s2 * u + s1 * q + s3 * p + s4;
    float g2 = s1 * p + s2;

    int j = threadIdx.x << 2;
    float4 bb1 = *(const float4*)&beta1p[j];
    float4 bb2 = *(const float4*)&beta2[j];
    float4 b3v = *(const float4*)&b3[j];
    floatx4 acc;
    acc.x = g1 * bb1.x + g2 * bb2.x + b3v.x;
    acc.y = g1 * bb1.y + g2 * bb2.y + b3v.y;
    acc.z = g1 * bb1.z + g2 * bb2.z + b3v.z;
    acc.w = g1 * bb1.w + g2 * bb2.w + b3v.w;

    #pragma unroll
    for (int i = 0; i < KF; ++i) {
        float4 h = *(const float4*)&H[(size_t)sc[i] * 1024 + j];
        acc.x += h.x;
        acc.y += h.y;
        acc.z += h.z;
        acc.w += h.w;
    }
    __builtin_nontemporal_store(acc, (floatx4*)&out[(size_t)r * 1024 + j]);
}

// ---------------------------------------------------------------------------
extern "C" void kernel_launch(void* const* d_in, const int* in_sizes, int n_in,
                              void* d_out, int out_size, void* d_ws, size_t ws_size,
                              hipStream_t stream) {
    const int*   x   = (const int*)d_in[0];
    const float* emb = (const float*)d_in[1];
    const float* Ws  = (const float*)d_in[2];
    const float* bsv = (const float*)d_in[3];
    float* out = (float*)d_out;

    char* ws = (char*)d_ws;
    const size_t MB = 1 << 20;
    int*   idx    = (int*)(ws);
    int*   cnt    = (int*)(ws + 0x40000);
    float* dv     = (float*)(ws + 0x41000);
    float* wGv    = (float*)(ws + 0x42000);
    float* wCv    = (float*)(ws + 0x43000);
    float* beta1p = (float*)(ws + 0x44000);
    float* beta2  = (float*)(ws + 0x45000);
    float* Mcnt   = (float*)(ws + 1 * MB);
    _Float16* Eh    = (_Float16*)(ws + 5 * MB);
    _Float16* El    = (_Float16*)(ws + 7 * MB);
    _Float16* W1th  = (_Float16*)(ws + 9 * MB);
    _Float16* W1tl  = (_Float16*)(ws + 11 * MB);
    _Float16* W2h   = (_Float16*)(ws + 13 * MB);
    _Float16* W2l   = (_Float16*)(ws + 15 * MB);
    _Float16* W3th  = (_Float16*)(ws + 17 * MB);
    _Float16* W3tl  = (_Float16*)(ws + 19 * MB);
    _Float16* Mph   = (_Float16*)(ws + 21 * MB);
    _Float16* Mpl   = (_Float16*)(ws + 23 * MB);
    _Float16* Ath   = (_Float16*)(ws + 25 * MB);
    _Float16* Atl   = (_Float16*)(ws + 27 * MB);
    _Float16* W23th = (_Float16*)(ws + 29 * MB);
    _Float16* W23tl = (_Float16*)(ws + 31 * MB);
    _Float16* Th    = (_Float16*)(ws + 33 * MB);
    _Float16* Tl    = (_Float16*)(ws + 35 * MB);
    float*    Hm    = (float*)(ws + 37 * MB);

    const float* W1 = Ws;
    const float* W2 = Ws + 1024 * 1024;
    const float* W3 = Ws + 2 * 1024 * 1024;
    const float* b1 = bsv;
    const float* b2 = bsv + 1024;
    const float* b3 = bsv + 2048;

    zero_ws<<<1024, 256, 0, stream>>>(Mcnt, cnt);

    extract_rows<<<N_ROWS / 4, 256, 0, stream>>>(x, idx, cnt);
    compute_w<<<IN_DIM / 256, 256, 0, stream>>>(cnt, dv, wGv, wCv);
    build_M<<<N_ROWS / 4, 256, 0, stream>>>(idx, Mcnt);

    split_nat<<<dim3(1024, 2), 256, 0, stream>>>(emb, W2, Eh, El, W2h, W2l);
    transp_split<<<dim3(16, 16, 2), 256, 0, stream>>>(W1, W3, W1th, W1tl, W3th, W3tl);
    scale_splitM<<<1024, 256, 0, stream>>>(Mcnt, dv, wGv, wCv, Mph, Mpl);

    // S1a: At = (E @ W1)^T ; S1b: W23t = (W2 @ W3)^T  -- one dispatch, z-select
    GemmDesc dS1a = {Eh, El, W1th, W1tl, nullptr, nullptr, nullptr, Ath, Atl};
    GemmDesc dS1b = {W2h, W2l, W3th, W3tl, nullptr, nullptr, nullptr, W23th, W23tl};
    gemm_split<<<dim3(16, 16, 2), 256, 0, stream>>>(dS1a, dS1b);

    // beta1p = b1 @ W23 ; beta2 = b2 @ W3
    vecmat_t<<<dim3(1024, 2), 256, 0, stream>>>(W23th, W23tl, b1, beta1p,
                                                W3th, W3tl, b2, beta2);

    // S2: T = M' @ A   (natural split out)
    GemmDesc dS2 = {Mph, Mpl, Ath, Atl, nullptr, Th, Tl, nullptr, nullptr};
    gemm_split<<<dim3(16, 16, 1), 256, 0, stream>>>(dS2, dS2);

    // S3: H = T @ W23  (f32 out)
    GemmDesc dS3 = {Th, Tl, W23th, W23tl, Hm, nullptr, nullptr, nullptr, nullptr};
    gemm_split<<<dim3(16, 16, 1), 256, 0, stream>>>(dS3, dS3);

    final_out<<<N_ROWS, 256, 0, stream>>>(Hm, idx, dv, beta1p, beta2, b3, out);
}

// Round 8
// 148.212 us; speedup vs baseline: 2.8567x; 1.0508x over previous
//
#include <hip/hip_runtime.h>

#define N_ROWS 8192
#define IN_DIM 1024
#define KF     8

typedef _Float16 half8 __attribute__((ext_vector_type(8)));
typedef _Float16 half4 __attribute__((ext_vector_type(4)));
typedef float    floatx4 __attribute__((ext_vector_type(4)));
typedef float    floatx16 __attribute__((ext_vector_type(16)));

__device__ __forceinline__ half8 ld_half8(const _Float16* p) {
    int4 t = *(const int4*)p;
    return __builtin_bit_cast(half8, t);
}
__device__ __forceinline__ void fsplit(float v, _Float16& h, _Float16& l) {
    _Float16 x = (_Float16)v;
    h = x;
    l = (_Float16)((v - (float)x) * 2048.0f);
}
__device__ __forceinline__ void gload16(const _Float16* g, _Float16* l) {
    __builtin_amdgcn_global_load_lds(
        (const __attribute__((address_space(1))) void*)g,
        (__attribute__((address_space(3))) void*)l,
        16, 0, 0);
}

// ---------------------------------------------------------------------------
__global__ void zero_ws(float* __restrict__ Mcnt, int* __restrict__ cnt) {
    size_t i = ((size_t)blockIdx.x * 256 + threadIdx.x) << 2;
    floatx4 z = {0.f, 0.f, 0.f, 0.f};
    *(floatx4*)&Mcnt[i] = z;
    if (blockIdx.x == 0) {
        int4 zi = {0, 0, 0, 0};
        *(int4*)&cnt[threadIdx.x << 2] = zi;
    }
}

// ---------------------------------------------------------------------------
// fused: extract per-row indices + per-feature counts + co-occurrence pairs
__global__ void extract_build(const int* __restrict__ x,
                              int* __restrict__ idx,
                              int* __restrict__ cnt,
                              float* __restrict__ M) {
    const int wv   = threadIdx.x >> 6;
    const int r    = blockIdx.x * 4 + wv;
    const int lane = threadIdx.x & 63;
    const int* row = x + (size_t)r * IN_DIM;

    __shared__ int cols[4][KF];

    int vals[16];
    #pragma unroll
    for (int j = 0; j < 4; ++j) {
        int4 v = ((const int4*)row)[lane * 4 + j];
        vals[j * 4 + 0] = v.x;
        vals[j * 4 + 1] = v.y;
        vals[j * 4 + 2] = v.z;
        vals[j * 4 + 3] = v.w;
    }
    int c = 0;
    #pragma unroll
    for (int j = 0; j < 16; ++j) c += (vals[j] != 0);

    int s = c;
    #pragma unroll
    for (int o = 1; o < 64; o <<= 1) {
        int t = __shfl_up(s, o, 64);
        if (lane >= o) s += t;
    }
    int pos = s - c;

    #pragma unroll
    for (int j = 0; j < 16; ++j) {
        if (vals[j] != 0) {
            int col = lane * 16 + j;
            if (pos < KF) {
                idx[r * KF + pos] = col;
                cols[wv][pos] = col;
            }
            pos++;
            atomicAdd(&cnt[col], 1);
        }
    }
    __syncthreads();
    // all 64 ordered pairs of this row's cols (i==j included -> diag)
    int ci = cols[wv][lane >> 3];
    int cj = cols[wv][lane & 7];
    atomicAdd(&M[ci * IN_DIM + cj], 1.0f);
}

// ---------------------------------------------------------------------------
// one dispatch: y = task id
//  0: split E       1: split W2      2: transp W1     3: transp W3
//  4: M' = diag(wG)*Mcnt*diag(d) + diag(wC), split
__global__ __launch_bounds__(256) void prep(
        const float* __restrict__ emb, const float* __restrict__ W1,
        const float* __restrict__ W2, const float* __restrict__ W3,
        const float* __restrict__ Mc, const int* __restrict__ cnt,
        _Float16* __restrict__ Eh, _Float16* __restrict__ El,
        _Float16* __restrict__ W1th, _Float16* __restrict__ W1tl,
        _Float16* __restrict__ W2h, _Float16* __restrict__ W2l,
        _Float16* __restrict__ W3th, _Float16* __restrict__ W3tl,
        _Float16* __restrict__ Mph, _Float16* __restrict__ Mpl) {
    const int task = blockIdx.y;
    const int bx   = blockIdx.x;

    if (task <= 1) {            // natural split
        const float* S = task ? W2 : emb;
        _Float16* Hp = task ? W2h : Eh;
        _Float16* Lp = task ? W2l : El;
        size_t i = ((size_t)bx * 256 + threadIdx.x) << 2;
        float4 v = *(const float4*)&S[i];
        float vv[4] = {v.x, v.y, v.z, v.w};
        half4 h, l;
        #pragma unroll
        for (int j = 0; j < 4; ++j) { _Float16 hh, ll; fsplit(vv[j], hh, ll); h[j] = hh; l[j] = ll; }
        *(int2*)&Hp[i] = __builtin_bit_cast(int2, h);
        *(int2*)&Lp[i] = __builtin_bit_cast(int2, l);
        return;
    }
    if (task <= 3) {            // transposed split
        if (bx >= 256) return;
        const float* S = (task == 3) ? W3 : W1;
        _Float16* Hp = (task == 3) ? W3th : W1th;
        _Float16* Lp = (task == 3) ? W3tl : W1tl;
        __shared__ float sh[64][65];
        const int r0 = (bx >> 4) << 6, c0 = (bx & 15) << 6;
        #pragma unroll
        for (int it = 0; it < 4; ++it) {
            int r = (threadIdx.x >> 4) + (it << 4);
            int c = (threadIdx.x & 15) << 2;
            float4 v = *(const float4*)&S[(size_t)(r0 + r) * 1024 + c0 + c];
            sh[r][c] = v.x; sh[r][c + 1] = v.y; sh[r][c + 2] = v.z; sh[r][c + 3] = v.w;
        }
        __syncthreads();
        int nl = threadIdx.x >> 2;
        #pragma unroll
        for (int cc = 0; cc < 2; ++cc) {
            int kq = ((threadIdx.x & 3) << 4) + (cc << 3);
            half8 h, l;
            #pragma unroll
            for (int j = 0; j < 8; ++j) {
                _Float16 hh, ll;
                fsplit(sh[kq + j][nl], hh, ll);
                h[j] = hh; l[j] = ll;
            }
            *(int4*)&Hp[(size_t)(c0 + nl) * 1024 + r0 + kq] = __builtin_bit_cast(int4, h);
            *(int4*)&Lp[(size_t)(c0 + nl) * 1024 + r0 + kq] = __builtin_bit_cast(int4, l);
        }
        return;
    }
    // task 4: scale+split M'
    const float s1 = 1.f / 3.f, s3 = 1.f / 27.f, s5 = 1.f / 243.f;
    size_t i = ((size_t)bx * 256 + threadIdx.x) << 2;
    int row = (int)(i >> 10);
    int cb  = (int)(i & 1023);
    float dr  = rsqrtf((float)cnt[row] + 1.0f);
    float d2  = dr * dr;
    float wg  = s3 * d2;
    float wc  = dr * (s1 * d2 * d2 + s3 * d2 + s5);
    int4 c4 = *(const int4*)&cnt[cb];
    float4 m  = *(const float4*)&Mc[i];
    float v[4];
    v[0] = m.x * rsqrtf((float)c4.x + 1.0f) * wg;
    v[1] = m.y * rsqrtf((float)c4.y + 1.0f) * wg;
    v[2] = m.z * rsqrtf((float)c4.z + 1.0f) * wg;
    v[3] = m.w * rsqrtf((float)c4.w + 1.0f) * wg;
    #pragma unroll
    for (int j = 0; j < 4; ++j)
        if (cb + j == row) v[j] += wc;
    half4 h, l;
    #pragma unroll
    for (int j = 0; j < 4; ++j) { _Float16 hh, ll; fsplit(v[j], hh, ll); h[j] = hh; l[j] = ll; }
    *(int2*)&Mph[i] = __builtin_bit_cast(int2, h);
    *(int2*)&Mpl[i] = __builtin_bit_cast(int2, l);
}

// ---------------------------------------------------------------------------
// split-f16 MFMA GEMM: 64x64 tile, 4 waves, one 32x32x16 chain per wave,
// THREE independent accumulator chains (hh / h*l / l*h), BK=64, dbuf LDS
// via global_load_lds w=16, pre-swizzled source + swizzled ds_read (T2).
struct GemmDesc {
    const _Float16 *Ah, *Al;   // A natural [m][k]
    const _Float16 *Bh, *Bl;   // B transposed [n][k]
    float* Df;                 // optional f32 out
    _Float16 *Dnh, *Dnl;       // optional natural split out
    _Float16 *Dth, *Dtl;       // optional transposed split out
};

__global__ __launch_bounds__(256) void gemm_split(GemmDesc d0, GemmDesc d1)
{
    GemmDesc d = blockIdx.z ? d1 : d0;
    __shared__ _Float16 lds[2][4][64][64];   // [buf][Ah,Al,Bh,Bl][row][k] 64 KB

    const int tid  = threadIdx.x;
    const int lane = tid & 63;
    const int w    = tid >> 6;
    const int wm   = w >> 1, wn = w & 1;
    const int brow = blockIdx.y << 6;
    const int bcol = blockIdx.x << 6;

    const _Float16* gsrc = (w == 0) ? d.Ah : (w == 1) ? d.Al : (w == 2) ? d.Bh : d.Bl;
    const int rowbase = (w < 2) ? brow : bcol;
    const int swz = (((lane & 7) ^ ((lane >> 3) & 7)) << 3);
    const _Float16* gbase = gsrc + (size_t)(rowbase + (lane >> 3)) * 1024 + swz;

#define STAGE(kt_, buf_) do {                                              \
        _Float16* lb = &lds[buf_][w][0][0];                                \
        const _Float16* gb = gbase + ((kt_) << 6);                         \
        _Pragma("unroll")                                                  \
        for (int c = 0; c < 8; ++c)                                        \
            gload16(gb + ((size_t)(c << 3) << 10), lb + (c << 9));         \
    } while (0)

    const int l31  = lane & 31;
    const int kh   = lane >> 5;
    const int arow = (wm << 5) + l31;
    const int brw  = (wn << 5) + l31;
    const int r7   = l31 & 7;

    floatx16 acc0 = {};
    floatx16 acc1 = {};
    floatx16 acc2 = {};

    STAGE(0, 0);
    __syncthreads();

    int cur = 0;
    for (int kt = 0; kt < 16; ++kt) {
        if (kt < 15) STAGE(kt + 1, cur ^ 1);
        const _Float16* pa_h = &lds[cur][0][arow][0];
        const _Float16* pa_l = &lds[cur][1][arow][0];
        const _Float16* pb_h = &lds[cur][2][brw][0];
        const _Float16* pb_l = &lds[cur][3][brw][0];
        #pragma unroll
        for (int kc = 0; kc < 4; ++kc) {
            int ca = ((((kc << 1) | kh) ^ r7) << 3);
            half8 ah = ld_half8(pa_h + ca);
            half8 al = ld_half8(pa_l + ca);
            half8 bh = ld_half8(pb_h + ca);
            half8 bl = ld_half8(pb_l + ca);
            acc0 = __builtin_amdgcn_mfma_f32_32x32x16_f16(ah, bh, acc0, 0, 0, 0);
            acc1 = __builtin_amdgcn_mfma_f32_32x32x16_f16(ah, bl, acc1, 0, 0, 0);
            acc2 = __builtin_amdgcn_mfma_f32_32x32x16_f16(al, bh, acc2, 0, 0, 0);
        }
        if (kt < 15) {
            __syncthreads();
            cur ^= 1;
        }
    }
#undef STAGE

    // epilogue: C/D layout col=lane&31, row=(r&3)+8*(r>>2)+4*(lane>>5)
    const float is = 1.0f / 2048.0f;
    const int grow = brow + (wm << 5) + (kh << 2);
    const int gcol = bcol + (wn << 5) + l31;

    if (d.Df) {
        #pragma unroll
        for (int r = 0; r < 16; ++r) {
            int row = grow + (r & 3) + ((r >> 2) << 3);
            d.Df[(size_t)row * 1024 + gcol] = acc0[r] + (acc1[r] + acc2[r]) * is;
        }
    }
    if (d.Dnh) {
        #pragma unroll
        for (int r = 0; r < 16; ++r) {
            int row = grow + (r & 3) + ((r >> 2) << 3);
            _Float16 h, l;
            fsplit(acc0[r] + (acc1[r] + acc2[r]) * is, h, l);
            d.Dnh[(size_t)row * 1024 + gcol] = h;
            d.Dnl[(size_t)row * 1024 + gcol] = l;
        }
    }
    if (d.Dth) {
        #pragma unroll
        for (int g = 0; g < 4; ++g) {
            half4 hv, lv;
            #pragma unroll
            for (int j = 0; j < 4; ++j) {
                int r = (g << 2) + j;
                _Float16 h, l;
                fsplit(acc0[r] + (acc1[r] + acc2[r]) * is, h, l);
                hv[j] = h; lv[j] = l;
            }
            int row = grow + (g << 3);
            *(int2*)&d.Dth[(size_t)gcol * 1024 + row] = __builtin_bit_cast(int2, hv);
            *(int2*)&d.Dtl[(size_t)gcol * 1024 + row] = __builtin_bit_cast(int2, lv);
        }
    }
}

// y[n] = sum_k (Wt_h[n][k] + Wt_l[n][k]/2048) * v[k]; two problems via blockIdx.y
__global__ __launch_bounds__(256) void vecmat_t(
        const _Float16* __restrict__ Wh0, const _Float16* __restrict__ Wl0,
        const float* __restrict__ v0, float* __restrict__ y0,
        const _Float16* __restrict__ Wh1, const _Float16* __restrict__ Wl1,
        const float* __restrict__ v1, float* __restrict__ y1) {
    const _Float16* Wh = blockIdx.y ? Wh1 : Wh0;
    const _Float16* Wl = blockIdx.y ? Wl1 : Wl0;
    const float*    vv = blockIdx.y ? v1 : v0;
    float*          yy = blockIdx.y ? y1 : y0;
    const float is = 1.0f / 2048.0f;
    int n  = blockIdx.x;
    int k0 = threadIdx.x << 2;
    int2 th = *(const int2*)&Wh[(size_t)n * 1024 + k0];
    int2 tl = *(const int2*)&Wl[(size_t)n * 1024 + k0];
    half4 h = __builtin_bit_cast(half4, th);
    half4 l = __builtin_bit_cast(half4, tl);
    float4 b = *(const float4*)&vv[k0];
    float acc = ((float)h[0] + (float)l[0] * is) * b.x
              + ((float)h[1] + (float)l[1] * is) * b.y
              + ((float)h[2] + (float)l[2] * is) * b.z
              + ((float)h[3] + (float)l[3] * is) * b.w;
    #pragma unroll
    for (int o = 1; o < 64; o <<= 1) acc += __shfl_xor(acc, o, 64);
    __shared__ float red[4];
    if ((threadIdx.x & 63) == 0) red[threadIdx.x >> 6] = acc;
    __syncthreads();
    if (threadIdx.x == 0) yy[n] = red[0] + red[1] + red[2] + red[3];
}

// ---------------------------------------------------------------------------
// out[r] = sum_i H[c_i] + g1*beta1p + g2*beta2 + b3
__global__ __launch_bounds__(256) void final_out(const float* __restrict__ H,
                                                 const int* __restrict__ idx,
                                                 const int* __restrict__ cnt,
                                                 const float* __restrict__ beta1p,
                                                 const float* __restrict__ beta2,
                                                 const float* __restrict__ b3,
                                                 float* __restrict__ out) {
    const int r = blockIdx.x;
    __shared__ int   sc[KF];
    __shared__ float sd[KF];
    if (threadIdx.x < KF) {
        int c = idx[r * KF + threadIdx.x];
        sc[threadIdx.x] = c;
        sd[threadIdx.x] = rsqrtf((float)cnt[c] + 1.0f);
    }
    __syncthreads();

    const float s1 = 1.f / 3.f, s2 = 1.f / 9.f, s3 = 1.f / 27.f, s4 = 1.f / 81.f;

    float p = 0.f, q = 0.f, sum2 = 0.f;
    #pragma unroll
    for (int i = 0; i < KF; ++i) {
        float dd = sd[i];
        p += dd;
        sum2 += dd * dd;
        q += dd * dd * dd;
    }
    float u  = (float)KF - sum2;
    float g1 = s2 * u + s1 * q + s3 * p + s4;
    float g2 = s1 * p + s2;

    int j = threadIdx.x << 2;
    float4 bb1 = *(const float4*)&beta1p[j];
    float4 bb2 = *(const float4*)&beta2[j];
    float4 b3v = *(const float4*)&b3[j];
    floatx4 acc;
    acc.x = g1 * bb1.x + g2 * bb2.x + b3v.x;
    acc.y = g1 * bb1.y + g2 * bb2.y + b3v.y;
    acc.z = g1 * bb1.z + g2 * bb2.z + b3v.z;
    acc.w = g1 * bb1.w + g2 * bb2.w + b3v.w;

    #pragma unroll
    for (int i = 0; i < KF; ++i) {
        float4 h = *(const float4*)&H[(size_t)sc[i] * 1024 + j];
        acc.x += h.x;
        acc.y += h.y;
        acc.z += h.z;
        acc.w += h.w;
    }
    __builtin_nontemporal_store(acc, (floatx4*)&out[(size_t)r * 1024 + j]);
}

// ---------------------------------------------------------------------------
extern "C" void kernel_launch(void* const* d_in, const int* in_sizes, int n_in,
                              void* d_out, int out_size, void* d_ws, size_t ws_size,
                              hipStream_t stream) {
    const int*   x   = (const int*)d_in[0];
    const float* emb = (const float*)d_in[1];
    const float* Ws  = (const float*)d_in[2];
    const float* bsv = (const float*)d_in[3];
    float* out = (float*)d_out;

    char* ws = (char*)d_ws;
    const size_t MB = 1 << 20;
    int*   idx    = (int*)(ws);
    int*   cnt    = (int*)(ws + 0x40000);
    float* beta1p = (float*)(ws + 0x44000);
    float* beta2  = (float*)(ws + 0x45000);
    float* Mcnt   = (float*)(ws + 1 * MB);
    _Float16* Eh    = (_Float16*)(ws + 5 * MB);
    _Float16* El    = (_Float16*)(ws + 7 * MB);
    _Float16* W1th  = (_Float16*)(ws + 9 * MB);
    _Float16* W1tl  = (_Float16*)(ws + 11 * MB);
    _Float16* W2h   = (_Float16*)(ws + 13 * MB);
    _Float16* W2l   = (_Float16*)(ws + 15 * MB);
    _Float16* W3th  = (_Float16*)(ws + 17 * MB);
    _Float16* W3tl  = (_Float16*)(ws + 19 * MB);
    _Float16* Mph   = (_Float16*)(ws + 21 * MB);
    _Float16* Mpl   = (_Float16*)(ws + 23 * MB);
    _Float16* Ath   = (_Float16*)(ws + 25 * MB);
    _Float16* Atl   = (_Float16*)(ws + 27 * MB);
    _Float16* W23th = (_Float16*)(ws + 29 * MB);
    _Float16* W23tl = (_Float16*)(ws + 31 * MB);
    _Float16* Th    = (_Float16*)(ws + 33 * MB);
    _Float16* Tl    = (_Float16*)(ws + 35 * MB);
    float*    Hm    = (float*)(ws + 37 * MB);

    const float* W1 = Ws;
    const float* W2 = Ws + 1024 * 1024;
    const float* W3 = Ws + 2 * 1024 * 1024;
    const float* b1 = bsv;
    const float* b2 = bsv + 1024;
    const float* b3 = bsv + 2048;

    zero_ws<<<1024, 256, 0, stream>>>(Mcnt, cnt);

    extract_build<<<N_ROWS / 4, 256, 0, stream>>>(x, idx, cnt, Mcnt);

    prep<<<dim3(1024, 5), 256, 0, stream>>>(emb, W1, W2, W3, Mcnt, cnt,
        Eh, El, W1th, W1tl, W2h, W2l, W3th, W3tl, Mph, Mpl);

    // S1a: At = (E @ W1)^T ; S1b: W23t = (W2 @ W3)^T  -- one dispatch
    GemmDesc dS1a = {Eh, El, W1th, W1tl, nullptr, nullptr, nullptr, Ath, Atl};
    GemmDesc dS1b = {W2h, W2l, W3th, W3tl, nullptr, nullptr, nullptr, W23th, W23tl};
    gemm_split<<<dim3(16, 16, 2), 256, 0, stream>>>(dS1a, dS1b);

    // beta1p = b1 @ W23 ; beta2 = b2 @ W3
    vecmat_t<<<dim3(1024, 2), 256, 0, stream>>>(W23th, W23tl, b1, beta1p,
                                                W3th, W3tl, b2, beta2);

    // S2: T = M' @ A   (natural split out)
    GemmDesc dS2 = {Mph, Mpl, Ath, Atl, nullptr, Th, Tl, nullptr, nullptr};
    gemm_split<<<dim3(16, 16, 1), 256, 0, stream>>>(dS2, dS2);

    // S3: H = T @ W23  (f32 out)
    GemmDesc dS3 = {Th, Tl, W23th, W23tl, Hm, nullptr, nullptr, nullptr, nullptr};
    gemm_split<<<dim3(16, 16, 1), 256, 0, stream>>>(dS3, dS3);

    final_out<<<N_ROWS, 256, 0, stream>>>(Hm, idx, cnt, beta1p, beta2, b3, out);
}

// Round 9
// 138.960 us; speedup vs baseline: 3.0469x; 1.0666x over previous
//
#include <hip/hip_runtime.h>

#define N_ROWS 8192
#define IN_DIM 1024
#define KF     8

typedef _Float16 half8 __attribute__((ext_vector_type(8)));
typedef _Float16 half4 __attribute__((ext_vector_type(4)));
typedef float    floatx4 __attribute__((ext_vector_type(4)));
typedef float    floatx16 __attribute__((ext_vector_type(16)));

__device__ __forceinline__ half8 ld_half8(const _Float16* p) {
    int4 t = *(const int4*)p;
    return __builtin_bit_cast(half8, t);
}
__device__ __forceinline__ void fsplit(float v, _Float16& h, _Float16& l) {
    _Float16 x = (_Float16)v;
    h = x;
    l = (_Float16)((v - (float)x) * 2048.0f);
}
__device__ __forceinline__ void gload16(const _Float16* g, _Float16* l) {
    __builtin_amdgcn_global_load_lds(
        (const __attribute__((address_space(1))) void*)g,
        (__attribute__((address_space(3))) void*)l,
        16, 0, 0);
}

// ---------------------------------------------------------------------------
__global__ void zero_ws(float* __restrict__ Mcnt, int* __restrict__ cnt) {
    size_t i = ((size_t)blockIdx.x * 256 + threadIdx.x) << 2;
    floatx4 z = {0.f, 0.f, 0.f, 0.f};
    *(floatx4*)&Mcnt[i] = z;
    if (blockIdx.x == 0) {
        int4 zi = {0, 0, 0, 0};
        *(int4*)&cnt[threadIdx.x << 2] = zi;
    }
}

// ---------------------------------------------------------------------------
// fused: extract per-row indices + per-feature counts + co-occurrence pairs.
// Pair atomics emit UPPER TRIANGLE ONLY (cols ascending -> ci<=cj): 36/64
// atomics per row; prep task 4 symmetrizes U + U^T.
__global__ void extract_build(const int* __restrict__ x,
                              int* __restrict__ idx,
                              int* __restrict__ cnt,
                              float* __restrict__ M) {
    const int wv   = threadIdx.x >> 6;
    const int r    = blockIdx.x * 4 + wv;
    const int lane = threadIdx.x & 63;
    const int* row = x + (size_t)r * IN_DIM;

    __shared__ int cols[4][KF];

    int vals[16];
    #pragma unroll
    for (int j = 0; j < 4; ++j) {
        int4 v = ((const int4*)row)[lane * 4 + j];
        vals[j * 4 + 0] = v.x;
        vals[j * 4 + 1] = v.y;
        vals[j * 4 + 2] = v.z;
        vals[j * 4 + 3] = v.w;
    }
    int c = 0;
    #pragma unroll
    for (int j = 0; j < 16; ++j) c += (vals[j] != 0);

    int s = c;
    #pragma unroll
    for (int o = 1; o < 64; o <<= 1) {
        int t = __shfl_up(s, o, 64);
        if (lane >= o) s += t;
    }
    int pos = s - c;

    #pragma unroll
    for (int j = 0; j < 16; ++j) {
        if (vals[j] != 0) {
            int col = lane * 16 + j;
            if (pos < KF) {
                idx[r * KF + pos] = col;
                cols[wv][pos] = col;
            }
            pos++;
            atomicAdd(&cnt[col], 1);
        }
    }
    __syncthreads();
    // upper-triangle pairs (incl diagonal): 36 atomics per row
    int i = lane >> 3, j = lane & 7;
    if (i <= j) {
        int ci = cols[wv][i];
        int cj = cols[wv][j];          // ci <= cj (ascending extraction)
        atomicAdd(&M[ci * IN_DIM + cj], 1.0f);
    }
}

// ---------------------------------------------------------------------------
// one dispatch: y = task id
//  0: split E       1: split W2      2: transp W1     3: transp W3
//  4: M' = diag(wG)*(U+U^T)*diag(d) + diag(wC), split (tiled symmetrize)
__global__ __launch_bounds__(256) void prep(
        const float* __restrict__ emb, const float* __restrict__ W1,
        const float* __restrict__ W2, const float* __restrict__ W3,
        const float* __restrict__ Mc, const int* __restrict__ cnt,
        _Float16* __restrict__ Eh, _Float16* __restrict__ El,
        _Float16* __restrict__ W1th, _Float16* __restrict__ W1tl,
        _Float16* __restrict__ W2h, _Float16* __restrict__ W2l,
        _Float16* __restrict__ W3th, _Float16* __restrict__ W3tl,
        _Float16* __restrict__ Mph, _Float16* __restrict__ Mpl) {
    const int task = blockIdx.y;
    const int bx   = blockIdx.x;

    if (task <= 1) {            // natural split
        const float* S = task ? W2 : emb;
        _Float16* Hp = task ? W2h : Eh;
        _Float16* Lp = task ? W2l : El;
        size_t i = ((size_t)bx * 256 + threadIdx.x) << 2;
        float4 v = *(const float4*)&S[i];
        float vv[4] = {v.x, v.y, v.z, v.w};
        half4 h, l;
        #pragma unroll
        for (int j = 0; j < 4; ++j) { _Float16 hh, ll; fsplit(vv[j], hh, ll); h[j] = hh; l[j] = ll; }
        *(int2*)&Hp[i] = __builtin_bit_cast(int2, h);
        *(int2*)&Lp[i] = __builtin_bit_cast(int2, l);
        return;
    }
    if (task <= 3) {            // transposed split
        if (bx >= 256) return;
        const float* S = (task == 3) ? W3 : W1;
        _Float16* Hp = (task == 3) ? W3th : W1th;
        _Float16* Lp = (task == 3) ? W3tl : W1tl;
        __shared__ float sh[64][65];
        const int r0 = (bx >> 4) << 6, c0 = (bx & 15) << 6;
        #pragma unroll
        for (int it = 0; it < 4; ++it) {
            int r = (threadIdx.x >> 4) + (it << 4);
            int c = (threadIdx.x & 15) << 2;
            float4 v = *(const float4*)&S[(size_t)(r0 + r) * 1024 + c0 + c];
            sh[r][c] = v.x; sh[r][c + 1] = v.y; sh[r][c + 2] = v.z; sh[r][c + 3] = v.w;
        }
        __syncthreads();
        int nl = threadIdx.x >> 2;
        #pragma unroll
        for (int cc = 0; cc < 2; ++cc) {
            int kq = ((threadIdx.x & 3) << 4) + (cc << 3);
            half8 h, l;
            #pragma unroll
            for (int j = 0; j < 8; ++j) {
                _Float16 hh, ll;
                fsplit(sh[kq + j][nl], hh, ll);
                h[j] = hh; l[j] = ll;
            }
            *(int4*)&Hp[(size_t)(c0 + nl) * 1024 + r0 + kq] = __builtin_bit_cast(int4, h);
            *(int4*)&Lp[(size_t)(c0 + nl) * 1024 + r0 + kq] = __builtin_bit_cast(int4, l);
        }
        return;
    }
    // task 4: tiled symmetrize + scale + split
    // Mfull[i][j] = (i==j) ? U[i][i] : U[i][j] + U[j][i]
    if (bx >= 256) return;
    const int i0 = (bx >> 4) << 6;
    const int j0 = (bx & 15) << 6;
    __shared__ float tU[64][65];            // tU[r][c] = U[j0+r][i0+c]
    #pragma unroll
    for (int it = 0; it < 4; ++it) {
        int r = (threadIdx.x >> 4) + (it << 4);
        int c = (threadIdx.x & 15) << 2;
        float4 v = *(const float4*)&Mc[(size_t)(j0 + r) * 1024 + i0 + c];
        tU[r][c] = v.x; tU[r][c + 1] = v.y; tU[r][c + 2] = v.z; tU[r][c + 3] = v.w;
    }
    __syncthreads();

    const float s1 = 1.f / 3.f, s3 = 1.f / 27.f, s5 = 1.f / 243.f;
    const int ii = threadIdx.x >> 2;
    const int gi = i0 + ii;
    float dr = rsqrtf((float)cnt[gi] + 1.0f);
    float d2 = dr * dr;
    float wg = s3 * d2;
    float wc = dr * (s1 * d2 * d2 + s3 * d2 + s5);

    #pragma unroll
    for (int q = 0; q < 4; ++q) {
        int jj = ((threadIdx.x & 3) << 4) + (q << 2);
        size_t gidx = (size_t)gi * 1024 + j0 + jj;
        float4 un = *(const float4*)&Mc[gidx];
        int4 c4 = *(const int4*)&cnt[j0 + jj];
        float uv[4] = {un.x, un.y, un.z, un.w};
        int   cv[4] = {c4.x, c4.y, c4.z, c4.w};
        half4 h, l;
        #pragma unroll
        for (int t = 0; t < 4; ++t) {
            int gj = j0 + jj + t;
            float m = (gi == gj) ? uv[t] : (uv[t] + tU[jj + t][ii]);
            float dd = rsqrtf((float)cv[t] + 1.0f);
            float v = m * dd * wg + ((gi == gj) ? wc : 0.f);
            _Float16 hh, ll;
            fsplit(v, hh, ll);
            h[t] = hh; l[t] = ll;
        }
        *(int2*)&Mph[gidx] = __builtin_bit_cast(int2, h);
        *(int2*)&Mpl[gidx] = __builtin_bit_cast(int2, l);
    }
}

// ---------------------------------------------------------------------------
// split-f16 MFMA GEMM: 64x64 tile, 4 waves, one 32x32x16 chain per wave,
// THREE independent accumulator chains (hh / h*l / l*h), BK=64, dbuf LDS
// via global_load_lds w=16, pre-swizzled source + swizzled ds_read (T2).
struct GemmDesc {
    const _Float16 *Ah, *Al;   // A natural [m][k]
    const _Float16 *Bh, *Bl;   // B transposed [n][k]
    float* Df;                 // optional f32 out
    _Float16 *Dnh, *Dnl;       // optional natural split out
    _Float16 *Dth, *Dtl;       // optional transposed split out
};

__global__ __launch_bounds__(256) void gemm_split(GemmDesc d0, GemmDesc d1)
{
    GemmDesc d = blockIdx.z ? d1 : d0;
    __shared__ _Float16 lds[2][4][64][64];   // [buf][Ah,Al,Bh,Bl][row][k] 64 KB

    const int tid  = threadIdx.x;
    const int lane = tid & 63;
    const int w    = tid >> 6;
    const int wm   = w >> 1, wn = w & 1;
    const int brow = blockIdx.y << 6;
    const int bcol = blockIdx.x << 6;

    const _Float16* gsrc = (w == 0) ? d.Ah : (w == 1) ? d.Al : (w == 2) ? d.Bh : d.Bl;
    const int rowbase = (w < 2) ? brow : bcol;
    const int swz = (((lane & 7) ^ ((lane >> 3) & 7)) << 3);
    const _Float16* gbase = gsrc + (size_t)(rowbase + (lane >> 3)) * 1024 + swz;

#define STAGE(kt_, buf_) do {                                              \
        _Float16* lb = &lds[buf_][w][0][0];                                \
        const _Float16* gb = gbase + ((kt_) << 6);                         \
        _Pragma("unroll")                                                  \
        for (int c = 0; c < 8; ++c)                                        \
            gload16(gb + ((size_t)(c << 3) << 10), lb + (c << 9));         \
    } while (0)

    const int l31  = lane & 31;
    const int kh   = lane >> 5;
    const int arow = (wm << 5) + l31;
    const int brw  = (wn << 5) + l31;
    const int r7   = l31 & 7;

    floatx16 acc0 = {};
    floatx16 acc1 = {};
    floatx16 acc2 = {};

    STAGE(0, 0);
    __syncthreads();

    int cur = 0;
    for (int kt = 0; kt < 16; ++kt) {
        if (kt < 15) STAGE(kt + 1, cur ^ 1);
        const _Float16* pa_h = &lds[cur][0][arow][0];
        const _Float16* pa_l = &lds[cur][1][arow][0];
        const _Float16* pb_h = &lds[cur][2][brw][0];
        const _Float16* pb_l = &lds[cur][3][brw][0];
        #pragma unroll
        for (int kc = 0; kc < 4; ++kc) {
            int ca = ((((kc << 1) | kh) ^ r7) << 3);
            half8 ah = ld_half8(pa_h + ca);
            half8 al = ld_half8(pa_l + ca);
            half8 bh = ld_half8(pb_h + ca);
            half8 bl = ld_half8(pb_l + ca);
            acc0 = __builtin_amdgcn_mfma_f32_32x32x16_f16(ah, bh, acc0, 0, 0, 0);
            acc1 = __builtin_amdgcn_mfma_f32_32x32x16_f16(ah, bl, acc1, 0, 0, 0);
            acc2 = __builtin_amdgcn_mfma_f32_32x32x16_f16(al, bh, acc2, 0, 0, 0);
        }
        if (kt < 15) {
            __syncthreads();
            cur ^= 1;
        }
    }
#undef STAGE

    // epilogue: C/D layout col=lane&31, row=(r&3)+8*(r>>2)+4*(lane>>5)
    const float is = 1.0f / 2048.0f;
    const int grow = brow + (wm << 5) + (kh << 2);
    const int gcol = bcol + (wn << 5) + l31;

    if (d.Df) {
        #pragma unroll
        for (int r = 0; r < 16; ++r) {
            int row = grow + (r & 3) + ((r >> 2) << 3);
            d.Df[(size_t)row * 1024 + gcol] = acc0[r] + (acc1[r] + acc2[r]) * is;
        }
    }
    if (d.Dnh) {
        #pragma unroll
        for (int r = 0; r < 16; ++r) {
            int row = grow + (r & 3) + ((r >> 2) << 3);
            _Float16 h, l;
            fsplit(acc0[r] + (acc1[r] + acc2[r]) * is, h, l);
            d.Dnh[(size_t)row * 1024 + gcol] = h;
            d.Dnl[(size_t)row * 1024 + gcol] = l;
        }
    }
    if (d.Dth) {
        #pragma unroll
        for (int g = 0; g < 4; ++g) {
            half4 hv, lv;
            #pragma unroll
            for (int j = 0; j < 4; ++j) {
                int r = (g << 2) + j;
                _Float16 h, l;
                fsplit(acc0[r] + (acc1[r] + acc2[r]) * is, h, l);
                hv[j] = h; lv[j] = l;
            }
            int row = grow + (g << 3);
            *(int2*)&d.Dth[(size_t)gcol * 1024 + row] = __builtin_bit_cast(int2, hv);
            *(int2*)&d.Dtl[(size_t)gcol * 1024 + row] = __builtin_bit_cast(int2, lv);
        }
    }
}

// y[n] = sum_k (Wt_h[n][k] + Wt_l[n][k]/2048) * v[k]; two problems via blockIdx.y
__global__ __launch_bounds__(256) void vecmat_t(
        const _Float16* __restrict__ Wh0, const _Float16* __restrict__ Wl0,
        const float* __restrict__ v0, float* __restrict__ y0,
        const _Float16* __restrict__ Wh1, const _Float16* __restrict__ Wl1,
        const float* __restrict__ v1, float* __restrict__ y1) {
    const _Float16* Wh = blockIdx.y ? Wh1 : Wh0;
    const _Float16* Wl = blockIdx.y ? Wl1 : Wl0;
    const float*    vv = blockIdx.y ? v1 : v0;
    float*          yy = blockIdx.y ? y1 : y0;
    const float is = 1.0f / 2048.0f;
    int n  = blockIdx.x;
    int k0 = threadIdx.x << 2;
    int2 th = *(const int2*)&Wh[(size_t)n * 1024 + k0];
    int2 tl = *(const int2*)&Wl[(size_t)n * 1024 + k0];
    half4 h = __builtin_bit_cast(half4, th);
    half4 l = __builtin_bit_cast(half4, tl);
    float4 b = *(const float4*)&vv[k0];
    float acc = ((float)h[0] + (float)l[0] * is) * b.x
              + ((float)h[1] + (float)l[1] * is) * b.y
              + ((float)h[2] + (float)l[2] * is) * b.z
              + ((float)h[3] + (float)l[3] * is) * b.w;
    #pragma unroll
    for (int o = 1; o < 64; o <<= 1) acc += __shfl_xor(acc, o, 64);
    __shared__ float red[4];
    if ((threadIdx.x & 63) == 0) red[threadIdx.x >> 6] = acc;
    __syncthreads();
    if (threadIdx.x == 0) yy[n] = red[0] + red[1] + red[2] + red[3];
}

// ---------------------------------------------------------------------------
// out[r] = sum_i H[c_i] + g1*beta1p + g2*beta2 + b3
__global__ __launch_bounds__(256) void final_out(const float* __restrict__ H,
                                                 const int* __restrict__ idx,
                                                 const int* __restrict__ cnt,
                                                 const float* __restrict__ beta1p,
                                                 const float* __restrict__ beta2,
                                                 const float* __restrict__ b3,
                                                 float* __restrict__ out) {
    const int r = blockIdx.x;
    __shared__ int   sc[KF];
    __shared__ float sd[KF];
    if (threadIdx.x < KF) {
        int c = idx[r * KF + threadIdx.x];
        sc[threadIdx.x] = c;
        sd[threadIdx.x] = rsqrtf((float)cnt[c] + 1.0f);
    }
    __syncthreads();

    const float s1 = 1.f / 3.f, s2 = 1.f / 9.f, s3 = 1.f / 27.f, s4 = 1.f / 81.f;

    float p = 0.f, q = 0.f, sum2 = 0.f;
    #pragma unroll
    for (int i = 0; i < KF; ++i) {
        float dd = sd[i];
        p += dd;
        sum2 += dd * dd;
        q += dd * dd * dd;
    }
    float u  = (float)KF - sum2;
    float g1 = s2 * u + s1 * q + s3 * p + s4;
    float g2 = s1 * p + s2;

    int j = threadIdx.x << 2;
    float4 bb1 = *(const float4*)&beta1p[j];
    float4 bb2 = *(const float4*)&beta2[j];
    float4 b3v = *(const float4*)&b3[j];
    floatx4 acc;
    acc.x = g1 * bb1.x + g2 * bb2.x + b3v.x;
    acc.y = g1 * bb1.y + g2 * bb2.y + b3v.y;
    acc.z = g1 * bb1.z + g2 * bb2.z + b3v.z;
    acc.w = g1 * bb1.w + g2 * bb2.w + b3v.w;

    #pragma unroll
    for (int i = 0; i < KF; ++i) {
        float4 h = *(const float4*)&H[(size_t)sc[i] * 1024 + j];
        acc.x += h.x;
        acc.y += h.y;
        acc.z += h.z;
        acc.w += h.w;
    }
    __builtin_nontemporal_store(acc, (floatx4*)&out[(size_t)r * 1024 + j]);
}

// ---------------------------------------------------------------------------
extern "C" void kernel_launch(void* const* d_in, const int* in_sizes, int n_in,
                              void* d_out, int out_size, void* d_ws, size_t ws_size,
                              hipStream_t stream) {
    const int*   x   = (const int*)d_in[0];
    const float* emb = (const float*)d_in[1];
    const float* Ws  = (const float*)d_in[2];
    const float* bsv = (const float*)d_in[3];
    float* out = (float*)d_out;

    char* ws = (char*)d_ws;
    const size_t MB = 1 << 20;
    int*   idx    = (int*)(ws);
    int*   cnt    = (int*)(ws + 0x40000);
    float* beta1p = (float*)(ws + 0x44000);
    float* beta2  = (float*)(ws + 0x45000);
    float* Mcnt   = (float*)(ws + 1 * MB);
    _Float16* Eh    = (_Float16*)(ws + 5 * MB);
    _Float16* El    = (_Float16*)(ws + 7 * MB);
    _Float16* W1th  = (_Float16*)(ws + 9 * MB);
    _Float16* W1tl  = (_Float16*)(ws + 11 * MB);
    _Float16* W2h   = (_Float16*)(ws + 13 * MB);
    _Float16* W2l   = (_Float16*)(ws + 15 * MB);
    _Float16* W3th  = (_Float16*)(ws + 17 * MB);
    _Float16* W3tl  = (_Float16*)(ws + 19 * MB);
    _Float16* Mph   = (_Float16*)(ws + 21 * MB);
    _Float16* Mpl   = (_Float16*)(ws + 23 * MB);
    _Float16* Ath   = (_Float16*)(ws + 25 * MB);
    _Float16* Atl   = (_Float16*)(ws + 27 * MB);
    _Float16* W23th = (_Float16*)(ws + 29 * MB);
    _Float16* W23tl = (_Float16*)(ws + 31 * MB);
    _Float16* Th    = (_Float16*)(ws + 33 * MB);
    _Float16* Tl    = (_Float16*)(ws + 35 * MB);
    float*    Hm    = (float*)(ws + 37 * MB);

    const float* W1 = Ws;
    const float* W2 = Ws + 1024 * 1024;
    const float* W3 = Ws + 2 * 1024 * 1024;
    const float* b1 = bsv;
    const float* b2 = bsv + 1024;
    const float* b3 = bsv + 2048;

    zero_ws<<<1024, 256, 0, stream>>>(Mcnt, cnt);

    extract_build<<<N_ROWS / 4, 256, 0, stream>>>(x, idx, cnt, Mcnt);

    prep<<<dim3(1024, 5), 256, 0, stream>>>(emb, W1, W2, W3, Mcnt, cnt,
        Eh, El, W1th, W1tl, W2h, W2l, W3th, W3tl, Mph, Mpl);

    // S1a: At = (E @ W1)^T ; S1b: W23t = (W2 @ W3)^T  -- one dispatch
    GemmDesc dS1a = {Eh, El, W1th, W1tl, nullptr, nullptr, nullptr, Ath, Atl};
    GemmDesc dS1b = {W2h, W2l, W3th, W3tl, nullptr, nullptr, nullptr, W23th, W23tl};
    gemm_split<<<dim3(16, 16, 2), 256, 0, stream>>>(dS1a, dS1b);

    // beta1p = b1 @ W23 ; beta2 = b2 @ W3
    vecmat_t<<<dim3(1024, 2), 256, 0, stream>>>(W23th, W23tl, b1, beta1p,
                                                W3th, W3tl, b2, beta2);

    // S2: T = M' @ A   (natural split out)
    GemmDesc dS2 = {Mph, Mpl, Ath, Atl, nullptr, Th, Tl, nullptr, nullptr};
    gemm_split<<<dim3(16, 16, 1), 256, 0, stream>>>(dS2, dS2);

    // S3: H = T @ W23  (f32 out)
    GemmDesc dS3 = {Th, Tl, W23th, W23tl, Hm, nullptr, nullptr, nullptr, nullptr};
    gemm_split<<<dim3(16, 16, 1), 256, 0, stream>>>(dS3, dS3);

    final_out<<<N_ROWS, 256, 0, stream>>>(Hm, idx, cnt, beta1p, beta2, b3, out);
}

// Round 10
// 122.061 us; speedup vs baseline: 3.4687x; 1.1384x over previous
//
#include <hip/hip_runtime.h>

#define N_ROWS 8192
#define IN_DIM 1024
#define KF     8

typedef _Float16 half8 __attribute__((ext_vector_type(8)));
typedef _Float16 half4 __attribute__((ext_vector_type(4)));
typedef float    floatx4 __attribute__((ext_vector_type(4)));
typedef float    floatx16 __attribute__((ext_vector_type(16)));

__device__ __forceinline__ half8 ld_half8(const _Float16* p) {
    int4 t = *(const int4*)p;
    return __builtin_bit_cast(half8, t);
}
__device__ __forceinline__ void fsplit(float v, _Float16& h, _Float16& l) {
    _Float16 x = (_Float16)v;
    h = x;
    l = (_Float16)((v - (float)x) * 2048.0f);
}
__device__ __forceinline__ void gload16(const _Float16* g, _Float16* l) {
    __builtin_amdgcn_global_load_lds(
        (const __attribute__((address_space(1))) void*)g,
        (__attribute__((address_space(3))) void*)l,
        16, 0, 0);
}

// ---------------------------------------------------------------------------
__global__ void zero_ws(float* __restrict__ Mcnt) {
    size_t i = ((size_t)blockIdx.x * 256 + threadIdx.x) << 2;
    floatx4 z = {0.f, 0.f, 0.f, 0.f};
    *(floatx4*)&Mcnt[i] = z;
}

// ---------------------------------------------------------------------------
// fused: extract per-row indices + upper-triangle co-occurrence pairs.
// Diagonal U[c][c] doubles as the per-feature count (i==j pair fires once
// per row containing c) -- NO separate cnt atomics.
__global__ void extract_build(const int* __restrict__ x,
                              int* __restrict__ idx,
                              float* __restrict__ M) {
    const int wv   = threadIdx.x >> 6;
    const int r    = blockIdx.x * 4 + wv;
    const int lane = threadIdx.x & 63;
    const int* row = x + (size_t)r * IN_DIM;

    __shared__ int cols[4][KF];

    int vals[16];
    #pragma unroll
    for (int j = 0; j < 4; ++j) {
        int4 v = ((const int4*)row)[lane * 4 + j];
        vals[j * 4 + 0] = v.x;
        vals[j * 4 + 1] = v.y;
        vals[j * 4 + 2] = v.z;
        vals[j * 4 + 3] = v.w;
    }
    int c = 0;
    #pragma unroll
    for (int j = 0; j < 16; ++j) c += (vals[j] != 0);

    int s = c;
    #pragma unroll
    for (int o = 1; o < 64; o <<= 1) {
        int t = __shfl_up(s, o, 64);
        if (lane >= o) s += t;
    }
    int pos = s - c;

    #pragma unroll
    for (int j = 0; j < 16; ++j) {
        if (vals[j] != 0) {
            int col = lane * 16 + j;
            if (pos < KF) {
                idx[r * KF + pos] = col;
                cols[wv][pos] = col;
            }
            pos++;
        }
    }
    __syncthreads();
    // upper-triangle pairs (incl diagonal): 36 atomics per row
    int i = lane >> 3, j = lane & 7;
    if (i <= j) {
        int ci = cols[wv][i];
        int cj = cols[wv][j];          // ci <= cj (ascending extraction)
        atomicAdd(&M[ci * IN_DIM + cj], 1.0f);
    }
}

// ---------------------------------------------------------------------------
// one dispatch: y = task id
//  0: split E       1: split W2      2: transp W1     3: transp W3
//  4: M' = diag(wG)*(U+U^T)*diag(d) + diag(wC), split (tiled symmetrize)
//     counts come from diag(U).
__global__ __launch_bounds__(256) void prep(
        const float* __restrict__ emb, const float* __restrict__ W1,
        const float* __restrict__ W2, const float* __restrict__ W3,
        const float* __restrict__ Mc,
        _Float16* __restrict__ Eh, _Float16* __restrict__ El,
        _Float16* __restrict__ W1th, _Float16* __restrict__ W1tl,
        _Float16* __restrict__ W2h, _Float16* __restrict__ W2l,
        _Float16* __restrict__ W3th, _Float16* __restrict__ W3tl,
        _Float16* __restrict__ Mph, _Float16* __restrict__ Mpl) {
    const int task = blockIdx.y;
    const int bx   = blockIdx.x;

    if (task <= 1) {            // natural split
        const float* S = task ? W2 : emb;
        _Float16* Hp = task ? W2h : Eh;
        _Float16* Lp = task ? W2l : El;
        size_t i = ((size_t)bx * 256 + threadIdx.x) << 2;
        float4 v = *(const float4*)&S[i];
        float vv[4] = {v.x, v.y, v.z, v.w};
        half4 h, l;
        #pragma unroll
        for (int j = 0; j < 4; ++j) { _Float16 hh, ll; fsplit(vv[j], hh, ll); h[j] = hh; l[j] = ll; }
        *(int2*)&Hp[i] = __builtin_bit_cast(int2, h);
        *(int2*)&Lp[i] = __builtin_bit_cast(int2, l);
        return;
    }
    if (task <= 3) {            // transposed split
        if (bx >= 256) return;
        const float* S = (task == 3) ? W3 : W1;
        _Float16* Hp = (task == 3) ? W3th : W1th;
        _Float16* Lp = (task == 3) ? W3tl : W1tl;
        __shared__ float sh[64][65];
        const int r0 = (bx >> 4) << 6, c0 = (bx & 15) << 6;
        #pragma unroll
        for (int it = 0; it < 4; ++it) {
            int r = (threadIdx.x >> 4) + (it << 4);
            int c = (threadIdx.x & 15) << 2;
            float4 v = *(const float4*)&S[(size_t)(r0 + r) * 1024 + c0 + c];
            sh[r][c] = v.x; sh[r][c + 1] = v.y; sh[r][c + 2] = v.z; sh[r][c + 3] = v.w;
        }
        __syncthreads();
        int nl = threadIdx.x >> 2;
        #pragma unroll
        for (int cc = 0; cc < 2; ++cc) {
            int kq = ((threadIdx.x & 3) << 4) + (cc << 3);
            half8 h, l;
            #pragma unroll
            for (int j = 0; j < 8; ++j) {
                _Float16 hh, ll;
                fsplit(sh[kq + j][nl], hh, ll);
                h[j] = hh; l[j] = ll;
            }
            *(int4*)&Hp[(size_t)(c0 + nl) * 1024 + r0 + kq] = __builtin_bit_cast(int4, h);
            *(int4*)&Lp[(size_t)(c0 + nl) * 1024 + r0 + kq] = __builtin_bit_cast(int4, l);
        }
        return;
    }
    // task 4: tiled symmetrize + scale + split; counts from diag(U)
    if (bx >= 256) return;
    const int i0 = (bx >> 4) << 6;
    const int j0 = (bx & 15) << 6;
    __shared__ float tU[64][65];            // tU[r][c] = U[j0+r][i0+c]
    __shared__ float ddi[64], ddj[64];      // rsqrt(diag+1) for row/col blocks
    #pragma unroll
    for (int it = 0; it < 4; ++it) {
        int r = (threadIdx.x >> 4) + (it << 4);
        int c = (threadIdx.x & 15) << 2;
        float4 v = *(const float4*)&Mc[(size_t)(j0 + r) * 1024 + i0 + c];
        tU[r][c] = v.x; tU[r][c + 1] = v.y; tU[r][c + 2] = v.z; tU[r][c + 3] = v.w;
    }
    if (threadIdx.x < 64) {
        int c = i0 + threadIdx.x;
        ddi[threadIdx.x] = rsqrtf(Mc[(size_t)c * 1025] + 1.0f);
    } else if (threadIdx.x < 128) {
        int t = threadIdx.x - 64;
        int c = j0 + t;
        ddj[t] = rsqrtf(Mc[(size_t)c * 1025] + 1.0f);
    }
    __syncthreads();

    const float s1 = 1.f / 3.f, s3 = 1.f / 27.f, s5 = 1.f / 243.f;
    const int ii = threadIdx.x >> 2;
    const int gi = i0 + ii;
    float dr = ddi[ii];
    float d2 = dr * dr;
    float wg = s3 * d2;
    float wc = dr * (s1 * d2 * d2 + s3 * d2 + s5);

    #pragma unroll
    for (int q = 0; q < 4; ++q) {
        int jj = ((threadIdx.x & 3) << 4) + (q << 2);
        size_t gidx = (size_t)gi * 1024 + j0 + jj;
        float4 un = *(const float4*)&Mc[gidx];
        float uv[4] = {un.x, un.y, un.z, un.w};
        half4 h, l;
        #pragma unroll
        for (int t = 0; t < 4; ++t) {
            int gj = j0 + jj + t;
            float m = (gi == gj) ? uv[t] : (uv[t] + tU[jj + t][ii]);
            float v = m * ddj[jj + t] * wg + ((gi == gj) ? wc : 0.f);
            _Float16 hh, ll;
            fsplit(v, hh, ll);
            h[t] = hh; l[t] = ll;
        }
        *(int2*)&Mph[gidx] = __builtin_bit_cast(int2, h);
        *(int2*)&Mpl[gidx] = __builtin_bit_cast(int2, l);
    }
}

// ---------------------------------------------------------------------------
// split-f16 MFMA GEMM: 64x64 tile, 4 waves, one 32x32x16 chain per wave,
// THREE independent accumulator chains (hh / h*l / l*h), BK=64, dbuf LDS
// via global_load_lds w=16, pre-swizzled source + swizzled ds_read (T2).
struct GemmDesc {
    const _Float16 *Ah, *Al;   // A natural [m][k]
    const _Float16 *Bh, *Bl;   // B transposed [n][k]
    float* Df;                 // optional f32 out
    _Float16 *Dnh, *Dnl;       // optional natural split out
    _Float16 *Dth, *Dtl;       // optional transposed split out
};

__global__ __launch_bounds__(256) void gemm_split(GemmDesc d0, GemmDesc d1)
{
    GemmDesc d = blockIdx.z ? d1 : d0;
    __shared__ _Float16 lds[2][4][64][64];   // [buf][Ah,Al,Bh,Bl][row][k] 64 KB

    const int tid  = threadIdx.x;
    const int lane = tid & 63;
    const int w    = tid >> 6;
    const int wm   = w >> 1, wn = w & 1;
    const int brow = blockIdx.y << 6;
    const int bcol = blockIdx.x << 6;

    const _Float16* gsrc = (w == 0) ? d.Ah : (w == 1) ? d.Al : (w == 2) ? d.Bh : d.Bl;
    const int rowbase = (w < 2) ? brow : bcol;
    const int swz = (((lane & 7) ^ ((lane >> 3) & 7)) << 3);
    const _Float16* gbase = gsrc + (size_t)(rowbase + (lane >> 3)) * 1024 + swz;

#define STAGE(kt_, buf_) do {                                              \
        _Float16* lb = &lds[buf_][w][0][0];                                \
        const _Float16* gb = gbase + ((kt_) << 6);                         \
        _Pragma("unroll")                                                  \
        for (int c = 0; c < 8; ++c)                                        \
            gload16(gb + ((size_t)(c << 3) << 10), lb + (c << 9));         \
    } while (0)

    const int l31  = lane & 31;
    const int kh   = lane >> 5;
    const int arow = (wm << 5) + l31;
    const int brw  = (wn << 5) + l31;
    const int r7   = l31 & 7;

    floatx16 acc0 = {};
    floatx16 acc1 = {};
    floatx16 acc2 = {};

    STAGE(0, 0);
    __syncthreads();

    int cur = 0;
    for (int kt = 0; kt < 16; ++kt) {
        if (kt < 15) STAGE(kt + 1, cur ^ 1);
        const _Float16* pa_h = &lds[cur][0][arow][0];
        const _Float16* pa_l = &lds[cur][1][arow][0];
        const _Float16* pb_h = &lds[cur][2][brw][0];
        const _Float16* pb_l = &lds[cur][3][brw][0];
        #pragma unroll
        for (int kc = 0; kc < 4; ++kc) {
            int ca = ((((kc << 1) | kh) ^ r7) << 3);
            half8 ah = ld_half8(pa_h + ca);
            half8 al = ld_half8(pa_l + ca);
            half8 bh = ld_half8(pb_h + ca);
            half8 bl = ld_half8(pb_l + ca);
            acc0 = __builtin_amdgcn_mfma_f32_32x32x16_f16(ah, bh, acc0, 0, 0, 0);
            acc1 = __builtin_amdgcn_mfma_f32_32x32x16_f16(ah, bl, acc1, 0, 0, 0);
            acc2 = __builtin_amdgcn_mfma_f32_32x32x16_f16(al, bh, acc2, 0, 0, 0);
        }
        if (kt < 15) {
            __syncthreads();
            cur ^= 1;
        }
    }
#undef STAGE

    // epilogue: C/D layout col=lane&31, row=(r&3)+8*(r>>2)+4*(lane>>5)
    const float is = 1.0f / 2048.0f;
    const int grow = brow + (wm << 5) + (kh << 2);
    const int gcol = bcol + (wn << 5) + l31;

    if (d.Df) {
        #pragma unroll
        for (int r = 0; r < 16; ++r) {
            int row = grow + (r & 3) + ((r >> 2) << 3);
            d.Df[(size_t)row * 1024 + gcol] = acc0[r] + (acc1[r] + acc2[r]) * is;
        }
    }
    if (d.Dnh) {
        #pragma unroll
        for (int r = 0; r < 16; ++r) {
            int row = grow + (r & 3) + ((r >> 2) << 3);
            _Float16 h, l;
            fsplit(acc0[r] + (acc1[r] + acc2[r]) * is, h, l);
            d.Dnh[(size_t)row * 1024 + gcol] = h;
            d.Dnl[(size_t)row * 1024 + gcol] = l;
        }
    }
    if (d.Dth) {
        #pragma unroll
        for (int g = 0; g < 4; ++g) {
            half4 hv, lv;
            #pragma unroll
            for (int j = 0; j < 4; ++j) {
                int r = (g << 2) + j;
                _Float16 h, l;
                fsplit(acc0[r] + (acc1[r] + acc2[r]) * is, h, l);
                hv[j] = h; lv[j] = l;
            }
            int row = grow + (g << 3);
            *(int2*)&d.Dth[(size_t)gcol * 1024 + row] = __builtin_bit_cast(int2, hv);
            *(int2*)&d.Dtl[(size_t)gcol * 1024 + row] = __builtin_bit_cast(int2, lv);
        }
    }
}

// y[n] = sum_k (Wt_h[n][k] + Wt_l[n][k]/2048) * v[k]; two problems via blockIdx.y
__global__ __launch_bounds__(256) void vecmat_t(
        const _Float16* __restrict__ Wh0, const _Float16* __restrict__ Wl0,
        const float* __restrict__ v0, float* __restrict__ y0,
        const _Float16* __restrict__ Wh1, const _Float16* __restrict__ Wl1,
        const float* __restrict__ v1, float* __restrict__ y1) {
    const _Float16* Wh = blockIdx.y ? Wh1 : Wh0;
    const _Float16* Wl = blockIdx.y ? Wl1 : Wl0;
    const float*    vv = blockIdx.y ? v1 : v0;
    float*          yy = blockIdx.y ? y1 : y0;
    const float is = 1.0f / 2048.0f;
    int n  = blockIdx.x;
    int k0 = threadIdx.x << 2;
    int2 th = *(const int2*)&Wh[(size_t)n * 1024 + k0];
    int2 tl = *(const int2*)&Wl[(size_t)n * 1024 + k0];
    half4 h = __builtin_bit_cast(half4, th);
    half4 l = __builtin_bit_cast(half4, tl);
    float4 b = *(const float4*)&vv[k0];
    float acc = ((float)h[0] + (float)l[0] * is) * b.x
              + ((float)h[1] + (float)l[1] * is) * b.y
              + ((float)h[2] + (float)l[2] * is) * b.z
              + ((float)h[3] + (float)l[3] * is) * b.w;
    #pragma unroll
    for (int o = 1; o < 64; o <<= 1) acc += __shfl_xor(acc, o, 64);
    __shared__ float red[4];
    if ((threadIdx.x & 63) == 0) red[threadIdx.x >> 6] = acc;
    __syncthreads();
    if (threadIdx.x == 0) yy[n] = red[0] + red[1] + red[2] + red[3];
}

// ---------------------------------------------------------------------------
// out[r] = sum_i H[c_i] + g1*beta1p + g2*beta2 + b3 ; counts from diag(U)
__global__ __launch_bounds__(256) void final_out(const float* __restrict__ H,
                                                 const int* __restrict__ idx,
                                                 const float* __restrict__ Mc,
                                                 const float* __restrict__ beta1p,
                                                 const float* __restrict__ beta2,
                                                 const float* __restrict__ b3,
                                                 float* __restrict__ out) {
    const int r = blockIdx.x;
    __shared__ int   sc[KF];
    __shared__ float sd[KF];
    if (threadIdx.x < KF) {
        int c = idx[r * KF + threadIdx.x];
        sc[threadIdx.x] = c;
        sd[threadIdx.x] = rsqrtf(Mc[(size_t)c * 1025] + 1.0f);
    }
    __syncthreads();

    const float s1 = 1.f / 3.f, s2 = 1.f / 9.f, s3 = 1.f / 27.f, s4 = 1.f / 81.f;

    float p = 0.f, q = 0.f, sum2 = 0.f;
    #pragma unroll
    for (int i = 0; i < KF; ++i) {
        float dd = sd[i];
        p += dd;
        sum2 += dd * dd;
        q += dd * dd * dd;
    }
    float u  = (float)KF - sum2;
    float g1 = s2 * u + s1 * q + s3 * p + s4;
    float g2 = s1 * p + s2;

    int j = threadIdx.x << 2;
    float4 bb1 = *(const float4*)&beta1p[j];
    float4 bb2 = *(const float4*)&beta2[j];
    float4 b3v = *(const float4*)&b3[j];
    floatx4 acc;
    acc.x = g1 * bb1.x + g2 * bb2.x + b3v.x;
    acc.y = g1 * bb1.y + g2 * bb2.y + b3v.y;
    acc.z = g1 * bb1.z + g2 * bb2.z + b3v.z;
    acc.w = g1 * bb1.w + g2 * bb2.w + b3v.w;

    #pragma unroll
    for (int i = 0; i < KF; ++i) {
        float4 h = *(const float4*)&H[(size_t)sc[i] * 1024 + j];
        acc.x += h.x;
        acc.y += h.y;
        acc.z += h.z;
        acc.w += h.w;
    }
    __builtin_nontemporal_store(acc, (floatx4*)&out[(size_t)r * 1024 + j]);
}

// ---------------------------------------------------------------------------
extern "C" void kernel_launch(void* const* d_in, const int* in_sizes, int n_in,
                              void* d_out, int out_size, void* d_ws, size_t ws_size,
                              hipStream_t stream) {
    const int*   x   = (const int*)d_in[0];
    const float* emb = (const float*)d_in[1];
    const float* Ws  = (const float*)d_in[2];
    const float* bsv = (const float*)d_in[3];
    float* out = (float*)d_out;

    char* ws = (char*)d_ws;
    const size_t MB = 1 << 20;
    int*   idx    = (int*)(ws);
    float* beta1p = (float*)(ws + 0x44000);
    float* beta2  = (float*)(ws + 0x45000);
    float* Mcnt   = (float*)(ws + 1 * MB);
    _Float16* Eh    = (_Float16*)(ws + 5 * MB);
    _Float16* El    = (_Float16*)(ws + 7 * MB);
    _Float16* W1th  = (_Float16*)(ws + 9 * MB);
    _Float16* W1tl  = (_Float16*)(ws + 11 * MB);
    _Float16* W2h   = (_Float16*)(ws + 13 * MB);
    _Float16* W2l   = (_Float16*)(ws + 15 * MB);
    _Float16* W3th  = (_Float16*)(ws + 17 * MB);
    _Float16* W3tl  = (_Float16*)(ws + 19 * MB);
    _Float16* Mph   = (_Float16*)(ws + 21 * MB);
    _Float16* Mpl   = (_Float16*)(ws + 23 * MB);
    _Float16* Ath   = (_Float16*)(ws + 25 * MB);
    _Float16* Atl   = (_Float16*)(ws + 27 * MB);
    _Float16* W23th = (_Float16*)(ws + 29 * MB);
    _Float16* W23tl = (_Float16*)(ws + 31 * MB);
    _Float16* Th    = (_Float16*)(ws + 33 * MB);
    _Float16* Tl    = (_Float16*)(ws + 35 * MB);
    float*    Hm    = (float*)(ws + 37 * MB);

    const float* W1 = Ws;
    const float* W2 = Ws + 1024 * 1024;
    const float* W3 = Ws + 2 * 1024 * 1024;
    const float* b1 = bsv;
    const float* b2 = bsv + 1024;
    const float* b3 = bsv + 2048;

    zero_ws<<<1024, 256, 0, stream>>>(Mcnt);

    extract_build<<<N_ROWS / 4, 256, 0, stream>>>(x, idx, Mcnt);

    prep<<<dim3(1024, 5), 256, 0, stream>>>(emb, W1, W2, W3, Mcnt,
        Eh, El, W1th, W1tl, W2h, W2l, W3th, W3tl, Mph, Mpl);

    // S1a: At = (E @ W1)^T ; S1b: W23t = (W2 @ W3)^T  -- one dispatch
    GemmDesc dS1a = {Eh, El, W1th, W1tl, nullptr, nullptr, nullptr, Ath, Atl};
    GemmDesc dS1b = {W2h, W2l, W3th, W3tl, nullptr, nullptr, nullptr, W23th, W23tl};
    gemm_split<<<dim3(16, 16, 2), 256, 0, stream>>>(dS1a, dS1b);

    // beta1p = b1 @ W23 ; beta2 = b2 @ W3
    vecmat_t<<<dim3(1024, 2), 256, 0, stream>>>(W23th, W23tl, b1, beta1p,
                                                W3th, W3tl, b2, beta2);

    // S2: T = M' @ A   (natural split out)
    GemmDesc dS2 = {Mph, Mpl, Ath, Atl, nullptr, Th, Tl, nullptr, nullptr};
    gemm_split<<<dim3(16, 16, 1), 256, 0, stream>>>(dS2, dS2);

    // S3: H = T @ W23  (f32 out)
    GemmDesc dS3 = {Th, Tl, W23th, W23tl, Hm, nullptr, nullptr, nullptr, nullptr};
    gemm_split<<<dim3(16, 16, 1), 256, 0, stream>>>(dS3, dS3);

    final_out<<<N_ROWS, 256, 0, stream>>>(Hm, idx, Mcnt, beta1p, beta2, b3, out);
}